// Round 1
// baseline (832.716 us; speedup 1.0000x reference)
//
#include <hip/hip_runtime.h>

#define NN 50000
#define NE 600000
#define DIM 128
#define NG 512
#define OC 16
#define BN_EPS 1e-5f

// ---------------------------------------------------------------- histogram
__global__ void k_hist(const int* __restrict__ dst, int* __restrict__ deg, int e) {
    int i = blockIdx.x * blockDim.x + threadIdx.x;
    if (i < e) atomicAdd(&deg[dst[i]], 1);
}

// ------------------------------------------------- single-block scan (N=50k)
__global__ void k_scan(const int* __restrict__ deg, int* __restrict__ row_start,
                       int* __restrict__ cursor, int n) {
    __shared__ int lds[1024];
    __shared__ int carry;
    int t = threadIdx.x;
    if (t == 0) carry = 0;
    __syncthreads();
    for (int base = 0; base < n; base += 1024) {
        int i = base + t;
        int v = (i < n) ? deg[i] : 0;
        lds[t] = v;
        __syncthreads();
#pragma unroll
        for (int off = 1; off < 1024; off <<= 1) {
            int add = (t >= off) ? lds[t - off] : 0;
            __syncthreads();
            lds[t] += add;
            __syncthreads();
        }
        int exc = carry + lds[t] - v;   // exclusive prefix
        if (i < n) { row_start[i] = exc; cursor[i] = exc; }
        int tot = lds[1023];
        __syncthreads();
        if (t == 0) carry += tot;
        __syncthreads();
    }
    if (t == 0) row_start[n] = carry;
}

// ---------------------------------------------------------------- scatter
__global__ void k_scatter(const int* __restrict__ src, const int* __restrict__ dst,
                          int* __restrict__ cursor, int* __restrict__ col, int e) {
    int i = blockIdx.x * blockDim.x + threadIdx.x;
    if (i < e) {
        int d = dst[i];
        int p = atomicAdd(&cursor[d], 1);
        col[p] = src[i];
    }
}

// ------------------------------------------------------------- aggregation
// out[i] = T(H[i]) + sum_{e: dst=e} T(H[src[e]]),  T = relu(x*scale+shift) or identity
template <int TRANSFORM>
__global__ void k_aggregate(const float* __restrict__ H, const int* __restrict__ rs,
                            const int* __restrict__ col, const float* __restrict__ ss,
                            float* __restrict__ out, int n) {
    int node = blockIdx.x * (blockDim.x >> 6) + (threadIdx.x >> 6);
    if (node >= n) return;
    int lane = threadIdx.x & 63;
    int c0 = lane * 2;
    float sc0 = 1.f, sc1 = 1.f, sh0 = 0.f, sh1 = 0.f;
    if (TRANSFORM) { sc0 = ss[c0]; sc1 = ss[c0 + 1]; sh0 = ss[128 + c0]; sh1 = ss[129 + c0]; }
    const float2* Hp = (const float2*)H;
    float2 v = Hp[(size_t)node * 64 + lane];
    float ax, ay;
    if (TRANSFORM) { ax = fmaxf(fmaf(v.x, sc0, sh0), 0.f); ay = fmaxf(fmaf(v.y, sc1, sh1), 0.f); }
    else { ax = v.x; ay = v.y; }
    int s = rs[node], e = rs[node + 1];
    int i = s;
    for (; i + 1 < e; i += 2) {
        int j0 = col[i], j1 = col[i + 1];
        float2 u0 = Hp[(size_t)j0 * 64 + lane];
        float2 u1 = Hp[(size_t)j1 * 64 + lane];
        if (TRANSFORM) {
            ax += fmaxf(fmaf(u0.x, sc0, sh0), 0.f) + fmaxf(fmaf(u1.x, sc0, sh0), 0.f);
            ay += fmaxf(fmaf(u0.y, sc1, sh1), 0.f) + fmaxf(fmaf(u1.y, sc1, sh1), 0.f);
        } else {
            ax += u0.x + u1.x;
            ay += u0.y + u1.y;
        }
    }
    if (i < e) {
        int j0 = col[i];
        float2 u0 = Hp[(size_t)j0 * 64 + lane];
        if (TRANSFORM) {
            ax += fmaxf(fmaf(u0.x, sc0, sh0), 0.f);
            ay += fmaxf(fmaf(u0.y, sc1, sh1), 0.f);
        } else { ax += u0.x; ay += u0.y; }
    }
    float2 o; o.x = ax; o.y = ay;
    ((float2*)out)[(size_t)node * 64 + lane] = o;
}

// ---------------------------------------------------------------- GEMM
// Z[n,128] = T(A[n,128]) @ W[128,128] + bias; accumulate col sum/sumsq into stats[256]
#define FMA4(ACC, S, WV)                                                       \
    ACC.x = fmaf(S, WV.x, ACC.x); ACC.y = fmaf(S, WV.y, ACC.y);                \
    ACC.z = fmaf(S, WV.z, ACC.z); ACC.w = fmaf(S, WV.w, ACC.w);

template <int TRANSFORM>
__global__ __launch_bounds__(256, 2) void k_gemm(
        const float* __restrict__ A, const float* __restrict__ W,
        const float* __restrict__ bias, const float* __restrict__ ss,
        float* __restrict__ Z, float* __restrict__ stats, int n) {
    __shared__ float Wl[64 * 128];   // 32 KB (half of W at a time)
    __shared__ float Al[32 * 128];   // 16 KB
    int tid = threadIdx.x;
    int rowBase = blockIdx.x * 32;

    // load A tile (with optional BN+ReLU transform)
    float4* Al4 = (float4*)Al;
#pragma unroll
    for (int i = 0; i < 4; i++) {
        int f4 = tid + 256 * i;        // 0..1023
        int r = f4 >> 5;               // 0..31
        int c4 = (f4 & 31) * 4;
        int row = rowBase + r;
        float4 v;
        if (row < n) {
            v = ((const float4*)(A + (size_t)row * 128))[f4 & 31];
            if (TRANSFORM) {
                v.x = fmaxf(fmaf(v.x, ss[c4], ss[128 + c4]), 0.f);
                v.y = fmaxf(fmaf(v.y, ss[c4 + 1], ss[129 + c4]), 0.f);
                v.z = fmaxf(fmaf(v.z, ss[c4 + 2], ss[130 + c4]), 0.f);
                v.w = fmaxf(fmaf(v.w, ss[c4 + 3], ss[131 + c4]), 0.f);
            }
        } else { v = make_float4(0.f, 0.f, 0.f, 0.f); }
        Al4[f4] = v;
    }

    int c4 = (tid & 31) * 4;
    int r0 = (tid >> 5) * 4;
    float4 acc[4];
    float4 binit = make_float4(bias[c4], bias[c4 + 1], bias[c4 + 2], bias[c4 + 3]);
#pragma unroll
    for (int r = 0; r < 4; r++) acc[r] = binit;

    const float4* W4 = (const float4*)W;
    float4* Wl4 = (float4*)Wl;
    for (int half = 0; half < 2; half++) {
        __syncthreads();   // A ready / previous compute done
#pragma unroll
        for (int i = 0; i < 8; i++) Wl4[tid + 256 * i] = W4[tid + 256 * i + half * 2048];
        __syncthreads();
#pragma unroll 2
        for (int kk = 0; kk < 64; kk += 4) {
            float4 a[4], w[4];
#pragma unroll
            for (int r = 0; r < 4; r++)
                a[r] = *(const float4*)&Al[(r0 + r) * 128 + half * 64 + kk];
#pragma unroll
            for (int j = 0; j < 4; j++)
                w[j] = *(const float4*)&Wl[(kk + j) * 128 + c4];
#pragma unroll
            for (int r = 0; r < 4; r++) {
                FMA4(acc[r], a[r].x, w[0]);
                FMA4(acc[r], a[r].y, w[1]);
                FMA4(acc[r], a[r].z, w[2]);
                FMA4(acc[r], a[r].w, w[3]);
            }
        }
    }

    // store Z
#pragma unroll
    for (int r = 0; r < 4; r++) {
        int row = rowBase + r0 + r;
        if (row < n) ((float4*)(Z + (size_t)row * 128))[tid & 31] = acc[r];
    }

    // column stats (reuse Al as 256-float scratch)
    __syncthreads();
    if (tid < 128) { Al[tid] = 0.f; Al[128 + tid] = 0.f; }
    __syncthreads();
    float s[4] = {0.f, 0.f, 0.f, 0.f}, q[4] = {0.f, 0.f, 0.f, 0.f};
#pragma unroll
    for (int r = 0; r < 4; r++) {
        if (rowBase + r0 + r < n) {
            s[0] += acc[r].x; q[0] += acc[r].x * acc[r].x;
            s[1] += acc[r].y; q[1] += acc[r].y * acc[r].y;
            s[2] += acc[r].z; q[2] += acc[r].z * acc[r].z;
            s[3] += acc[r].w; q[3] += acc[r].w * acc[r].w;
        }
    }
#pragma unroll
    for (int j = 0; j < 4; j++) {
        atomicAdd(&Al[c4 + j], s[j]);
        atomicAdd(&Al[128 + c4 + j], q[j]);
    }
    __syncthreads();
    if (tid < 128) {
        atomicAdd(&stats[tid], Al[tid]);
        atomicAdd(&stats[128 + tid], Al[128 + tid]);
    }
}

// ------------------------------------------------------------- BN finalize
__global__ void k_finalize(float* __restrict__ stats, const float* __restrict__ gamma,
                           const float* __restrict__ beta, float* __restrict__ ss, float invn) {
    int c = threadIdx.x;   // 128 threads
    float s = stats[c], qq = stats[128 + c];
    float m = s * invn;
    float var = fmaxf(qq * invn - m * m, 0.f);
    float rs = rsqrtf(var + BN_EPS);
    float sc = gamma[c] * rs;
    ss[c] = sc;
    ss[128 + c] = beta[c] - m * sc;
    stats[c] = 0.f;
    stats[128 + c] = 0.f;
}

// ---------------------------------------------------------------- pooling
__global__ void k_pool(const float* __restrict__ H, const int* __restrict__ batch,
                       const float* __restrict__ ss, float* __restrict__ pooled,
                       int* __restrict__ cnt, int n) {
    int node = blockIdx.x * (blockDim.x >> 6) + (threadIdx.x >> 6);
    if (node >= n) return;
    int lane = threadIdx.x & 63;
    int g = batch[node];
    int c0 = lane * 2;
    const float2* Hp = (const float2*)H;
    float2 v = Hp[(size_t)node * 64 + lane];
    float vx = fmaxf(fmaf(v.x, ss[c0], ss[128 + c0]), 0.f);
    float vy = fmaxf(fmaf(v.y, ss[c0 + 1], ss[129 + c0]), 0.f);
    atomicAdd(&pooled[g * 128 + c0], vx);
    atomicAdd(&pooled[g * 128 + c0 + 1], vy);
    if (lane == 0) atomicAdd(&cnt[g], 1);
}

__global__ void k_headdiv(const float* __restrict__ pooled, const int* __restrict__ cnt,
                          float* __restrict__ out) {
    int i = blockIdx.x * blockDim.x + threadIdx.x;
    if (i < NG * 128) {
        int g = i >> 7;
        float c = fmaxf((float)cnt[g], 1.f);
        out[i] = pooled[i] / c;
    }
}

// ----------------------------------------------------- final tiny GEMM (512x16)
__global__ void k_final(const float* __restrict__ Zh, const float* __restrict__ ss,
                        const float* __restrict__ Wc2, const float* __restrict__ bc2,
                        float* __restrict__ out) {
    __shared__ float Wl[128 * 16];   // 8 KB
    __shared__ float Al[32 * 128];   // 16 KB
    int tid = threadIdx.x;           // 512 threads, block handles 32 graphs
#pragma unroll
    for (int i = 0; i < 4; i++) Wl[tid + 512 * i] = Wc2[tid + 512 * i];
#pragma unroll
    for (int i = 0; i < 8; i++) {
        int idx = tid + 512 * i;         // 0..4095
        int gl = idx >> 7, k = idx & 127;
        float a = Zh[(size_t)(blockIdx.x * 32 + gl) * 128 + k];
        Al[idx] = fmaxf(fmaf(a, ss[k], ss[128 + k]), 0.f);
    }
    __syncthreads();
    int g = tid >> 4, c = tid & 15;
    float acc = bc2[c];
#pragma unroll 8
    for (int k = 0; k < 128; k++) acc = fmaf(Al[g * 128 + k], Wl[k * 16 + c], acc);
    out[(size_t)(blockIdx.x * 32 + g) * 16 + c] = acc;
}

// ================================================================ launch
extern "C" void kernel_launch(void* const* d_in, const int* in_sizes, int n_in,
                              void* d_out, int out_size, void* d_ws, size_t ws_size,
                              hipStream_t stream) {
    (void)in_sizes; (void)n_in; (void)out_size; (void)ws_size;
    const float* x    = (const float*)d_in[0];
    const int*   ei   = (const int*)d_in[1];
    const int*   srcv = ei;         // edge_index[0]
    const int*   dstv = ei + NE;    // edge_index[1]
    const int*   batch = (const int*)d_in[2];
    const float* W1s = (const float*)d_in[3];
    const float* b1s = (const float*)d_in[4];
    const float* g1s = (const float*)d_in[5];
    const float* be1s = (const float*)d_in[6];
    const float* W2s = (const float*)d_in[7];
    const float* b2s = (const float*)d_in[8];
    const float* gns = (const float*)d_in[9];
    const float* bns = (const float*)d_in[10];
    const float* Wc1 = (const float*)d_in[11];
    const float* bc1 = (const float*)d_in[12];
    const float* gc  = (const float*)d_in[13];
    const float* bec = (const float*)d_in[14];
    const float* Wc2 = (const float*)d_in[15];
    const float* bc2 = (const float*)d_in[16];
    float* out = (float*)d_out;

    char* ws = (char*)d_ws;
    size_t off = 0;
    auto alloc = [&](size_t bytes) -> char* {
        char* p = ws + off;
        off += (bytes + 255) & ~(size_t)255;
        return p;
    };
    // --- zero zone (memset each launch) ---
    int*   deg    = (int*)alloc(50048 * 4);
    float* stats  = (float*)alloc(256 * 4);
    float* pooled = (float*)alloc(NG * 128 * 4);
    int*   cnt    = (int*)alloc(NG * 4);
    size_t zeroBytes = off;
    // --- rest ---
    int*   row_start = (int*)alloc((NN + 64) * 4);
    int*   cursor    = (int*)alloc((NN + 64) * 4);
    int*   col       = (int*)alloc((NE + 64) * 4);
    float* ssA   = (float*)alloc(256 * 4);
    float* ssB   = (float*)alloc(256 * 4);
    float* headA = (float*)alloc(NG * 128 * 4);
    float* bufA  = (float*)alloc((size_t)NN * 128 * 4);
    float* bufB  = (float*)alloc((size_t)NN * 128 * 4);
    float* bufC  = (float*)alloc((size_t)NN * 128 * 4);

    hipMemsetAsync(d_ws, 0, zeroBytes, stream);

    // CSR build (reused by all 3 layers)
    k_hist<<<(NE + 255) / 256, 256, 0, stream>>>(dstv, deg, NE);
    k_scan<<<1, 1024, 0, stream>>>(deg, row_start, cursor, NN);
    k_scatter<<<(NE + 255) / 256, 256, 0, stream>>>(srcv, dstv, cursor, col, NE);

    int aggGrid = (NN + 3) / 4;
    int gemmGrid = (NN + 31) / 32;
    for (int l = 0; l < 3; l++) {
        if (l == 0)
            k_aggregate<0><<<aggGrid, 256, 0, stream>>>(x, row_start, col, nullptr, bufA, NN);
        else
            k_aggregate<1><<<aggGrid, 256, 0, stream>>>(bufC, row_start, col, ssB, bufA, NN);
        k_gemm<0><<<gemmGrid, 256, 0, stream>>>(bufA, W1s + (size_t)l * 16384,
                                                b1s + l * 128, nullptr, bufB, stats, NN);
        k_finalize<<<1, 128, 0, stream>>>(stats, g1s + l * 128, be1s + l * 128, ssA, 1.f / NN);
        k_gemm<1><<<gemmGrid, 256, 0, stream>>>(bufB, W2s + (size_t)l * 16384,
                                                b2s + l * 128, ssA, bufC, stats, NN);
        k_finalize<<<1, 128, 0, stream>>>(stats, gns + l * 128, bns + l * 128, ssB, 1.f / NN);
    }

    // pooling + head
    k_pool<<<aggGrid, 256, 0, stream>>>(bufC, batch, ssB, pooled, cnt, NN);
    k_headdiv<<<(NG * 128 + 255) / 256, 256, 0, stream>>>(pooled, cnt, headA);
    k_gemm<0><<<(NG + 31) / 32, 256, 0, stream>>>(headA, Wc1, bc1, nullptr, bufB, stats, NG);
    k_finalize<<<1, 128, 0, stream>>>(stats, gc, bec, ssA, 1.f / NG);
    k_final<<<16, 512, 0, stream>>>(bufB, ssA, Wc2, bc2, out);
}

// Round 3
// 657.054 us; speedup vs baseline: 1.2673x; 1.2673x over previous
//
#include <hip/hip_runtime.h>

#define NN 50000
#define NE 600000
#define DIM 128
#define NG 512
#define OC 16
#define BN_EPS 1e-5f

// ---------------------------------------------------------------- histogram
__global__ void k_hist(const int* __restrict__ dst, int* __restrict__ deg, int e) {
    int i = blockIdx.x * blockDim.x + threadIdx.x;
    if (i < e) atomicAdd(&deg[dst[i]], 1);
}

// ----------------------------------------------- hierarchical scan, stage 1
// 1024-element block scans: exclusive-within-block prefix + block sums
__global__ void k_scan1(const int* __restrict__ deg, int* __restrict__ pre,
                        int* __restrict__ bsum, int n) {
    __shared__ int lds[1024];
    int t = threadIdx.x;
    int i = blockIdx.x * 1024 + t;
    int v = (i < n) ? deg[i] : 0;
    lds[t] = v;
    __syncthreads();
#pragma unroll
    for (int off = 1; off < 1024; off <<= 1) {
        int add = (t >= off) ? lds[t - off] : 0;
        __syncthreads();
        lds[t] += add;
        __syncthreads();
    }
    if (i < n) pre[i] = lds[t] - v;   // exclusive within block
    if (t == 1023) bsum[blockIdx.x] = lds[1023];
}

// ----------------------------------------------- stage 2: scan block sums (nb<=64)
__global__ void k_scan2(int* __restrict__ bsum, int nb) {
    int t = threadIdx.x;   // 64 threads
    int v = (t < nb) ? bsum[t] : 0;
    int orig = v;
#pragma unroll
    for (int off = 1; off < 64; off <<= 1) {
        int u = __shfl_up(v, off);
        if (t >= off) v += u;
    }
    if (t < nb) bsum[t] = v - orig;   // exclusive
}

// ----------------------------------------------- stage 3: add offsets
__global__ void k_scan3(const int* __restrict__ pre, const int* __restrict__ bsum,
                        int* __restrict__ row_start, int* __restrict__ cursor, int n) {
    int i = blockIdx.x * blockDim.x + threadIdx.x;
    if (i < n) {
        int r = pre[i] + bsum[i >> 10];
        row_start[i] = r;
        cursor[i] = r;
    }
    if (i == 0) row_start[n] = NE;   // total degree == edge count
}

// ---------------------------------------------------------------- scatter
__global__ void k_scatter(const int* __restrict__ src, const int* __restrict__ dst,
                          int* __restrict__ cursor, int* __restrict__ col, int e) {
    int i = blockIdx.x * blockDim.x + threadIdx.x;
    if (i < e) {
        int d = dst[i];
        int p = atomicAdd(&cursor[d], 1);
        col[p] = src[i];
    }
}

// -------------------------------------------- graph boundaries (batch sorted)
__global__ void k_gstart(const int* __restrict__ batch, int* __restrict__ gstart, int n) {
    int i = blockIdx.x * blockDim.x + threadIdx.x;
    if (i >= n) return;
    int b = batch[i];
    int bp = (i == 0) ? -1 : batch[i - 1];
    for (int g = bp + 1; g <= b; g++) gstart[g] = i;
    if (i == n - 1) {
        for (int g = b + 1; g <= NG; g++) gstart[g] = n;
    }
}

// ------------------------------------------------------------- aggregation
// out[i] = T(H[i]) + sum_{e: dst=e} T(H[src[e]]),  T = relu(x*scale+shift) or identity
template <int TRANSFORM>
__global__ void k_aggregate(const float* __restrict__ H, const int* __restrict__ rs,
                            const int* __restrict__ col, const float* __restrict__ ss,
                            float* __restrict__ out, int n) {
    int node = blockIdx.x * (blockDim.x >> 6) + (threadIdx.x >> 6);
    if (node >= n) return;
    int lane = threadIdx.x & 63;
    int c0 = lane * 2;
    float sc0 = 1.f, sc1 = 1.f, sh0 = 0.f, sh1 = 0.f;
    if (TRANSFORM) { sc0 = ss[c0]; sc1 = ss[c0 + 1]; sh0 = ss[128 + c0]; sh1 = ss[129 + c0]; }
    const float2* Hp = (const float2*)H;
    float2 v = Hp[(size_t)node * 64 + lane];
    float ax, ay;
    if (TRANSFORM) { ax = fmaxf(fmaf(v.x, sc0, sh0), 0.f); ay = fmaxf(fmaf(v.y, sc1, sh1), 0.f); }
    else { ax = v.x; ay = v.y; }
    int s = rs[node], e = rs[node + 1];
    int i = s;
    for (; i + 1 < e; i += 2) {
        int j0 = col[i], j1 = col[i + 1];
        float2 u0 = Hp[(size_t)j0 * 64 + lane];
        float2 u1 = Hp[(size_t)j1 * 64 + lane];
        if (TRANSFORM) {
            ax += fmaxf(fmaf(u0.x, sc0, sh0), 0.f) + fmaxf(fmaf(u1.x, sc0, sh0), 0.f);
            ay += fmaxf(fmaf(u0.y, sc1, sh1), 0.f) + fmaxf(fmaf(u1.y, sc1, sh1), 0.f);
        } else {
            ax += u0.x + u1.x;
            ay += u0.y + u1.y;
        }
    }
    if (i < e) {
        int j0 = col[i];
        float2 u0 = Hp[(size_t)j0 * 64 + lane];
        if (TRANSFORM) {
            ax += fmaxf(fmaf(u0.x, sc0, sh0), 0.f);
            ay += fmaxf(fmaf(u0.y, sc1, sh1), 0.f);
        } else { ax += u0.x; ay += u0.y; }
    }
    float2 o; o.x = ax; o.y = ay;
    ((float2*)out)[(size_t)node * 64 + lane] = o;
}

// ---------------------------------------------------------------- GEMM
// Z[n,128] = T(A[n,128]) @ W[128,128] + bias; accumulate col sum/sumsq into stats[256]
#define FMA4(ACC, S, WV)                                                       \
    ACC.x = fmaf(S, WV.x, ACC.x); ACC.y = fmaf(S, WV.y, ACC.y);                \
    ACC.z = fmaf(S, WV.z, ACC.z); ACC.w = fmaf(S, WV.w, ACC.w);

template <int TRANSFORM>
__global__ __launch_bounds__(256, 2) void k_gemm(
        const float* __restrict__ A, const float* __restrict__ W,
        const float* __restrict__ bias, const float* __restrict__ ss,
        float* __restrict__ Z, float* __restrict__ stats, int n) {
    __shared__ float Wl[64 * 128];   // 32 KB (half of W at a time)
    __shared__ float Al[32 * 128];   // 16 KB
    int tid = threadIdx.x;
    int rowBase = blockIdx.x * 32;

    // load A tile (with optional BN+ReLU transform)
    float4* Al4 = (float4*)Al;
#pragma unroll
    for (int i = 0; i < 4; i++) {
        int f4 = tid + 256 * i;        // 0..1023
        int r = f4 >> 5;               // 0..31
        int c4 = (f4 & 31) * 4;
        int row = rowBase + r;
        float4 v;
        if (row < n) {
            v = ((const float4*)(A + (size_t)row * 128))[f4 & 31];
            if (TRANSFORM) {
                v.x = fmaxf(fmaf(v.x, ss[c4], ss[128 + c4]), 0.f);
                v.y = fmaxf(fmaf(v.y, ss[c4 + 1], ss[129 + c4]), 0.f);
                v.z = fmaxf(fmaf(v.z, ss[c4 + 2], ss[130 + c4]), 0.f);
                v.w = fmaxf(fmaf(v.w, ss[c4 + 3], ss[131 + c4]), 0.f);
            }
        } else { v = make_float4(0.f, 0.f, 0.f, 0.f); }
        Al4[f4] = v;
    }

    int c4 = (tid & 31) * 4;
    int r0 = (tid >> 5) * 4;
    float4 acc[4];
    float4 binit = make_float4(bias[c4], bias[c4 + 1], bias[c4 + 2], bias[c4 + 3]);
#pragma unroll
    for (int r = 0; r < 4; r++) acc[r] = binit;

    const float4* W4 = (const float4*)W;
    float4* Wl4 = (float4*)Wl;
    for (int half = 0; half < 2; half++) {
        __syncthreads();   // A ready / previous compute done
#pragma unroll
        for (int i = 0; i < 8; i++) Wl4[tid + 256 * i] = W4[tid + 256 * i + half * 2048];
        __syncthreads();
#pragma unroll 2
        for (int kk = 0; kk < 64; kk += 4) {
            float4 a[4], w[4];
#pragma unroll
            for (int r = 0; r < 4; r++)
                a[r] = *(const float4*)&Al[(r0 + r) * 128 + half * 64 + kk];
#pragma unroll
            for (int j = 0; j < 4; j++)
                w[j] = *(const float4*)&Wl[(kk + j) * 128 + c4];
#pragma unroll
            for (int r = 0; r < 4; r++) {
                FMA4(acc[r], a[r].x, w[0]);
                FMA4(acc[r], a[r].y, w[1]);
                FMA4(acc[r], a[r].z, w[2]);
                FMA4(acc[r], a[r].w, w[3]);
            }
        }
    }

    // store Z
#pragma unroll
    for (int r = 0; r < 4; r++) {
        int row = rowBase + r0 + r;
        if (row < n) ((float4*)(Z + (size_t)row * 128))[tid & 31] = acc[r];
    }

    // column stats (reuse Al as 256-float scratch)
    __syncthreads();
    if (tid < 128) { Al[tid] = 0.f; Al[128 + tid] = 0.f; }
    __syncthreads();
    float s[4] = {0.f, 0.f, 0.f, 0.f}, q[4] = {0.f, 0.f, 0.f, 0.f};
#pragma unroll
    for (int r = 0; r < 4; r++) {
        if (rowBase + r0 + r < n) {
            s[0] += acc[r].x; q[0] += acc[r].x * acc[r].x;
            s[1] += acc[r].y; q[1] += acc[r].y * acc[r].y;
            s[2] += acc[r].z; q[2] += acc[r].z * acc[r].z;
            s[3] += acc[r].w; q[3] += acc[r].w * acc[r].w;
        }
    }
#pragma unroll
    for (int j = 0; j < 4; j++) {
        atomicAdd(&Al[c4 + j], s[j]);
        atomicAdd(&Al[128 + c4 + j], q[j]);
    }
    __syncthreads();
    if (tid < 128) {
        atomicAdd(&stats[tid], Al[tid]);
        atomicAdd(&stats[128 + tid], Al[128 + tid]);
    }
}

// ------------------------------------------------------------- BN finalize
__global__ void k_finalize(float* __restrict__ stats, const float* __restrict__ gamma,
                           const float* __restrict__ beta, float* __restrict__ ss, float invn) {
    int c = threadIdx.x;   // 128 threads
    float s = stats[c], qq = stats[128 + c];
    float m = s * invn;
    float var = fmaxf(qq * invn - m * m, 0.f);
    float rs = rsqrtf(var + BN_EPS);
    float sc = gamma[c] * rs;
    ss[c] = sc;
    ss[128 + c] = beta[c] - m * sc;
    stats[c] = 0.f;
    stats[128 + c] = 0.f;
}

// --------------------------------------------- segmented pooling (no atomics)
// pooled[g] = mean over rows [gstart[g], gstart[g+1]) of relu(bn(H[row]))
__global__ void k_pool_seg(const float* __restrict__ H, const int* __restrict__ gstart,
                           const float* __restrict__ ss, float* __restrict__ out) {
    int g = blockIdx.x;
    int s = gstart[g], e = gstart[g + 1];
    int t = threadIdx.x;            // 256 threads = 4 waves
    int lane = t & 63, wave = t >> 6;
    int c0 = lane * 2;
    float sc0 = ss[c0], sc1 = ss[c0 + 1], sh0 = ss[128 + c0], sh1 = ss[129 + c0];
    const float2* Hp = (const float2*)H;
    float ax = 0.f, ay = 0.f;
    for (int r = s + wave; r < e; r += 4) {
        float2 v = Hp[(size_t)r * 64 + lane];
        ax += fmaxf(fmaf(v.x, sc0, sh0), 0.f);
        ay += fmaxf(fmaf(v.y, sc1, sh1), 0.f);
    }
    __shared__ float red[2][256];
    red[0][t] = ax;
    red[1][t] = ay;
    __syncthreads();
    if (wave == 0) {
        float inv = 1.f / fmaxf((float)(e - s), 1.f);
        float sx = red[0][lane] + red[0][64 + lane] + red[0][128 + lane] + red[0][192 + lane];
        float sy = red[1][lane] + red[1][64 + lane] + red[1][128 + lane] + red[1][192 + lane];
        out[g * 128 + c0] = sx * inv;
        out[g * 128 + c0 + 1] = sy * inv;
    }
}

// ----------------------------------------------------- final tiny GEMM (512x16)
__global__ void k_final(const float* __restrict__ Zh, const float* __restrict__ ss,
                        const float* __restrict__ Wc2, const float* __restrict__ bc2,
                        float* __restrict__ out) {
    __shared__ float Wl[128 * 16];   // 8 KB
    __shared__ float Al[32 * 128];   // 16 KB
    int tid = threadIdx.x;           // 512 threads, block handles 32 graphs
#pragma unroll
    for (int i = 0; i < 4; i++) Wl[tid + 512 * i] = Wc2[tid + 512 * i];
#pragma unroll
    for (int i = 0; i < 8; i++) {
        int idx = tid + 512 * i;         // 0..4095
        int gl = idx >> 7, k = idx & 127;
        float a = Zh[(size_t)(blockIdx.x * 32 + gl) * 128 + k];
        Al[idx] = fmaxf(fmaf(a, ss[k], ss[128 + k]), 0.f);
    }
    __syncthreads();
    int g = tid >> 4, c = tid & 15;
    float acc = bc2[c];
#pragma unroll 8
    for (int k = 0; k < 128; k++) acc = fmaf(Al[g * 128 + k], Wl[k * 16 + c], acc);
    out[(size_t)(blockIdx.x * 32 + g) * 16 + c] = acc;
}

// ================================================================ launch
extern "C" void kernel_launch(void* const* d_in, const int* in_sizes, int n_in,
                              void* d_out, int out_size, void* d_ws, size_t ws_size,
                              hipStream_t stream) {
    (void)in_sizes; (void)n_in; (void)out_size; (void)ws_size;
    const float* x    = (const float*)d_in[0];
    const int*   ei   = (const int*)d_in[1];
    const int*   srcv = ei;         // edge_index[0]
    const int*   dstv = ei + NE;    // edge_index[1]
    const int*   batch = (const int*)d_in[2];
    const float* W1s = (const float*)d_in[3];
    const float* b1s = (const float*)d_in[4];
    const float* g1s = (const float*)d_in[5];
    const float* be1s = (const float*)d_in[6];
    const float* W2s = (const float*)d_in[7];
    const float* b2s = (const float*)d_in[8];
    const float* gns = (const float*)d_in[9];
    const float* bns = (const float*)d_in[10];
    const float* Wc1 = (const float*)d_in[11];
    const float* bc1 = (const float*)d_in[12];
    const float* gc  = (const float*)d_in[13];
    const float* bec = (const float*)d_in[14];
    const float* Wc2 = (const float*)d_in[15];
    const float* bc2 = (const float*)d_in[16];
    float* out = (float*)d_out;

    char* ws = (char*)d_ws;
    size_t off = 0;
    auto alloc = [&](size_t bytes) -> char* {
        char* p = ws + off;
        off += (bytes + 255) & ~(size_t)255;
        return p;
    };
    // --- zero zone (memset each launch) ---
    int*   deg    = (int*)alloc(50048 * 4);
    float* stats  = (float*)alloc(256 * 4);
    size_t zeroBytes = off;
    // --- rest ---
    int*   row_start = (int*)alloc((NN + 64) * 4);
    int*   cursor    = (int*)alloc((NN + 64) * 4);
    int*   pre       = (int*)alloc((NN + 64) * 4);
    int*   bsum      = (int*)alloc(64 * 4);
    int*   col       = (int*)alloc((NE + 64) * 4);
    int*   gstart    = (int*)alloc((NG + 1) * 4);
    float* ssA   = (float*)alloc(256 * 4);
    float* ssB   = (float*)alloc(256 * 4);
    float* headA = (float*)alloc(NG * 128 * 4);
    float* bufA  = (float*)alloc((size_t)NN * 128 * 4);
    float* bufB  = (float*)alloc((size_t)NN * 128 * 4);
    float* bufC  = (float*)alloc((size_t)NN * 128 * 4);

    hipMemsetAsync(d_ws, 0, zeroBytes, stream);

    // CSR build (reused by all 3 layers) + graph boundaries
    k_hist<<<(NE + 255) / 256, 256, 0, stream>>>(dstv, deg, NE);
    int nb = (NN + 1023) / 1024;   // 49
    k_scan1<<<nb, 1024, 0, stream>>>(deg, pre, bsum, NN);
    k_scan2<<<1, 64, 0, stream>>>(bsum, nb);
    k_scan3<<<(NN + 255) / 256, 256, 0, stream>>>(pre, bsum, row_start, cursor, NN);
    k_scatter<<<(NE + 255) / 256, 256, 0, stream>>>(srcv, dstv, cursor, col, NE);
    k_gstart<<<(NN + 255) / 256, 256, 0, stream>>>(batch, gstart, NN);

    int aggGrid = (NN + 3) / 4;
    int gemmGrid = (NN + 31) / 32;
    for (int l = 0; l < 3; l++) {
        if (l == 0)
            k_aggregate<0><<<aggGrid, 256, 0, stream>>>(x, row_start, col, nullptr, bufA, NN);
        else
            k_aggregate<1><<<aggGrid, 256, 0, stream>>>(bufC, row_start, col, ssB, bufA, NN);
        k_gemm<0><<<gemmGrid, 256, 0, stream>>>(bufA, W1s + (size_t)l * 16384,
                                                b1s + l * 128, nullptr, bufB, stats, NN);
        k_finalize<<<1, 128, 0, stream>>>(stats, g1s + l * 128, be1s + l * 128, ssA, 1.f / NN);
        k_gemm<1><<<gemmGrid, 256, 0, stream>>>(bufB, W2s + (size_t)l * 16384,
                                                b2s + l * 128, ssA, bufC, stats, NN);
        k_finalize<<<1, 128, 0, stream>>>(stats, gns + l * 128, bns + l * 128, ssB, 1.f / NN);
    }

    // pooling + head
    k_pool_seg<<<NG, 256, 0, stream>>>(bufC, gstart, ssB, headA);
    k_gemm<0><<<(NG + 31) / 32, 256, 0, stream>>>(headA, Wc1, bc1, nullptr, bufB, stats, NG);
    k_finalize<<<1, 128, 0, stream>>>(stats, gc, bec, ssA, 1.f / NG);
    k_final<<<16, 512, 0, stream>>>(bufB, ssA, Wc2, bc2, out);
}

// Round 4
// 460.343 us; speedup vs baseline: 1.8089x; 1.4273x over previous
//
#include <hip/hip_runtime.h>

#define NN 50000
#define NE 600000
#define DIM 128
#define NG 512
#define OC 16
#define BN_EPS 1e-5f

typedef __attribute__((ext_vector_type(8))) short short8v;   // 8 bf16 (4 VGPR)
typedef __attribute__((ext_vector_type(4))) float f32x4;

__device__ inline unsigned short f2bf(float f) {
    unsigned u = __float_as_uint(f);
    u = u + 0x7FFF + ((u >> 16) & 1);     // RNE
    return (unsigned short)(u >> 16);
}
__device__ inline float bf2f(unsigned short h) {
    return __uint_as_float(((unsigned)h) << 16);
}

// ---------------------------------------------------------------- histogram
__global__ void k_hist(const int* __restrict__ dst, int* __restrict__ deg, int e) {
    int i = blockIdx.x * blockDim.x + threadIdx.x;
    if (i < e) atomicAdd(&deg[dst[i]], 1);
}

// ----------------------------------------------- hierarchical scan, stage 1
__global__ void k_scan1(const int* __restrict__ deg, int* __restrict__ pre,
                        int* __restrict__ bsum, int n) {
    __shared__ int lds[1024];
    int t = threadIdx.x;
    int i = blockIdx.x * 1024 + t;
    int v = (i < n) ? deg[i] : 0;
    lds[t] = v;
    __syncthreads();
#pragma unroll
    for (int off = 1; off < 1024; off <<= 1) {
        int add = (t >= off) ? lds[t - off] : 0;
        __syncthreads();
        lds[t] += add;
        __syncthreads();
    }
    if (i < n) pre[i] = lds[t] - v;
    if (t == 1023) bsum[blockIdx.x] = lds[1023];
}

__global__ void k_scan2(int* __restrict__ bsum, int nb) {
    int t = threadIdx.x;
    int v = (t < nb) ? bsum[t] : 0;
    int orig = v;
#pragma unroll
    for (int off = 1; off < 64; off <<= 1) {
        int u = __shfl_up(v, off);
        if (t >= off) v += u;
    }
    if (t < nb) bsum[t] = v - orig;
}

__global__ void k_scan3(const int* __restrict__ pre, const int* __restrict__ bsum,
                        int* __restrict__ row_start, int* __restrict__ cursor, int n) {
    int i = blockIdx.x * blockDim.x + threadIdx.x;
    if (i < n) {
        int r = pre[i] + bsum[i >> 10];
        row_start[i] = r;
        cursor[i] = r;
    }
    if (i == 0) row_start[n] = NE;
}

// ---------------------------------------------------------------- scatter
__global__ void k_scatter(const int* __restrict__ src, const int* __restrict__ dst,
                          int* __restrict__ cursor, int* __restrict__ col, int e) {
    int i = blockIdx.x * blockDim.x + threadIdx.x;
    if (i < e) {
        int d = dst[i];
        int p = atomicAdd(&cursor[d], 1);
        col[p] = src[i];
    }
}

// -------------------------------------------- graph boundaries (batch sorted)
__global__ void k_gstart(const int* __restrict__ batch, int* __restrict__ gstart, int n) {
    int i = blockIdx.x * blockDim.x + threadIdx.x;
    if (i >= n) return;
    int b = batch[i];
    int bp = (i == 0) ? -1 : batch[i - 1];
    for (int g = bp + 1; g <= b; g++) gstart[g] = i;
    if (i == n - 1) {
        for (int g = b + 1; g <= NG; g++) gstart[g] = n;
    }
}

// ------------------------------------------------------------- aggregation
template <int TRANSFORM>
__global__ void k_aggregate(const float* __restrict__ H, const int* __restrict__ rs,
                            const int* __restrict__ col, const float* __restrict__ ss,
                            float* __restrict__ out, int n) {
    int node = blockIdx.x * (blockDim.x >> 6) + (threadIdx.x >> 6);
    if (node >= n) return;
    int lane = threadIdx.x & 63;
    int c0 = lane * 2;
    float sc0 = 1.f, sc1 = 1.f, sh0 = 0.f, sh1 = 0.f;
    if (TRANSFORM) { sc0 = ss[c0]; sc1 = ss[c0 + 1]; sh0 = ss[128 + c0]; sh1 = ss[129 + c0]; }
    const float2* Hp = (const float2*)H;
    float2 v = Hp[(size_t)node * 64 + lane];
    float ax, ay;
    if (TRANSFORM) { ax = fmaxf(fmaf(v.x, sc0, sh0), 0.f); ay = fmaxf(fmaf(v.y, sc1, sh1), 0.f); }
    else { ax = v.x; ay = v.y; }
    int s = rs[node], e = rs[node + 1];
    int i = s;
    for (; i + 1 < e; i += 2) {
        int j0 = col[i], j1 = col[i + 1];
        float2 u0 = Hp[(size_t)j0 * 64 + lane];
        float2 u1 = Hp[(size_t)j1 * 64 + lane];
        if (TRANSFORM) {
            ax += fmaxf(fmaf(u0.x, sc0, sh0), 0.f) + fmaxf(fmaf(u1.x, sc0, sh0), 0.f);
            ay += fmaxf(fmaf(u0.y, sc1, sh1), 0.f) + fmaxf(fmaf(u1.y, sc1, sh1), 0.f);
        } else {
            ax += u0.x + u1.x;
            ay += u0.y + u1.y;
        }
    }
    if (i < e) {
        int j0 = col[i];
        float2 u0 = Hp[(size_t)j0 * 64 + lane];
        if (TRANSFORM) {
            ax += fmaxf(fmaf(u0.x, sc0, sh0), 0.f);
            ay += fmaxf(fmaf(u0.y, sc1, sh1), 0.f);
        } else { ax += u0.x; ay += u0.y; }
    }
    float2 o; o.x = ax; o.y = ay;
    ((float2*)out)[(size_t)node * 64 + lane] = o;
}

// --------------------------------------------- weight -> MFMA fragment prep
// For matrix m (0..2: W1s[l], 3..5: W2s[l-3], 6: Wc1), write hi/lo bf16 frags:
// wfrag[(m*2+term)*16384 + ((ct*4+k0)*64+lane)*8 + j]
//   = bf16 of W[k0*32+(lane>>4)*8+j][ct*16+(lane&15)]
__global__ void k_prepw(const float* __restrict__ W1s, const float* __restrict__ W2s,
                        const float* __restrict__ Wc1, unsigned short* __restrict__ wfrag) {
    int idx = blockIdx.x * blockDim.x + threadIdx.x;
    if (idx >= 7 * 8 * 4 * 64) return;
    int lane = idx & 63;
    int k0 = (idx >> 6) & 3;
    int ct = (idx >> 8) & 7;
    int m = idx >> 11;
    const float* Wsrc = (m < 3) ? (W1s + (size_t)m * 16384)
                      : (m < 6) ? (W2s + (size_t)(m - 3) * 16384)
                                : Wc1;
    int colc = ct * 16 + (lane & 15);
    int kbase = k0 * 32 + (lane >> 4) * 8;
    short8v hi, lo;
#pragma unroll
    for (int j = 0; j < 8; j++) {
        float w = Wsrc[(size_t)(kbase + j) * 128 + colc];
        unsigned short h = f2bf(w);
        hi[j] = (short)h;
        lo[j] = (short)f2bf(w - bf2f(h));
    }
    size_t fo = ((size_t)(ct * 4 + k0) * 64 + lane) * 8;
    *(short8v*)(wfrag + (size_t)(m * 2 + 0) * 16384 + fo) = hi;
    *(short8v*)(wfrag + (size_t)(m * 2 + 1) * 16384 + fo) = lo;
}

// --------------------------------------------- split-bf16 MFMA GEMM
// Z[n,128] = T(A[n,128]) @ W + bias, col sum/sumsq -> stats.
// One wave = 16-row strip. whi = frag base (hi); lo frags at +16384 elems.
#define MFMA(A8, B8, C4) __builtin_amdgcn_mfma_f32_16x16x32_bf16(A8, B8, C4, 0, 0, 0)

template <int TRANSFORM>
__global__ __launch_bounds__(256) void k_gemm_mfma(
        const float* __restrict__ A, const unsigned short* __restrict__ whi,
        const float* __restrict__ bias, const float* __restrict__ ss,
        float* __restrict__ Z, float* __restrict__ stats, int nstrips) {
    __shared__ float sred[256];
    int tid = threadIdx.x;
    int wid = tid >> 6, lane = tid & 63;
    int strip = blockIdx.x * 4 + wid;
    bool active = strip < nstrips;
    int row0 = strip * 16;
    int rlo = lane & 15, kb = lane >> 4;

    sred[tid] = 0.f;

    // --- A fragments (hi/lo split), row = row0+rlo, k = k0*32 + kb*8 + j ---
    short8v ahi[4], alo[4];
    if (active) {
#pragma unroll
        for (int k0 = 0; k0 < 4; k0++) {
            int c = k0 * 32 + kb * 8;
            const float* ap = A + (size_t)(row0 + rlo) * 128 + c;
            float4 v0 = *(const float4*)ap;
            float4 v1 = *(const float4*)(ap + 4);
            float f[8] = {v0.x, v0.y, v0.z, v0.w, v1.x, v1.y, v1.z, v1.w};
            if (TRANSFORM) {
#pragma unroll
                for (int j = 0; j < 8; j++)
                    f[j] = fmaxf(fmaf(f[j], ss[c + j], ss[128 + c + j]), 0.f);
            }
#pragma unroll
            for (int j = 0; j < 8; j++) {
                unsigned short h = f2bf(f[j]);
                ahi[k0][j] = (short)h;
                alo[k0][j] = (short)f2bf(f[j] - bf2f(h));
            }
        }
    }
    __syncthreads();   // sred zeroed

    const short8v* wh = (const short8v*)whi;
    const short8v* wl = wh + 2048;   // +16384 bf16 elems

    if (active) {
#pragma unroll
        for (int ctp = 0; ctp < 4; ctp++) {
            int ct0 = ctp * 2, ct1 = ctp * 2 + 1;
            float bb0 = bias[ct0 * 16 + rlo], bb1 = bias[ct1 * 16 + rlo];
            f32x4 acc0 = {bb0, bb0, bb0, bb0};
            f32x4 acc1 = {bb1, bb1, bb1, bb1};
            short8v bh0[4], bh1[4];
#pragma unroll
            for (int k0 = 0; k0 < 4; k0++) {
                bh0[k0] = wh[(ct0 * 4 + k0) * 64 + lane];
                bh1[k0] = wh[(ct1 * 4 + k0) * 64 + lane];
            }
#pragma unroll
            for (int k0 = 0; k0 < 4; k0++) {
                acc0 = MFMA(ahi[k0], bh0[k0], acc0);
                acc1 = MFMA(ahi[k0], bh1[k0], acc1);
            }
#pragma unroll
            for (int k0 = 0; k0 < 4; k0++) {
                short8v bl0 = wl[(ct0 * 4 + k0) * 64 + lane];
                short8v bl1 = wl[(ct1 * 4 + k0) * 64 + lane];
                acc0 = MFMA(ahi[k0], bl0, acc0);
                acc1 = MFMA(ahi[k0], bl1, acc1);
                acc0 = MFMA(alo[k0], bh0[k0], acc0);
                acc1 = MFMA(alo[k0], bh1[k0], acc1);
            }
            // store: C row = kb*4+j, col = ct*16+rlo
#pragma unroll
            for (int j = 0; j < 4; j++) {
                Z[(size_t)(row0 + kb * 4 + j) * 128 + ct0 * 16 + rlo] = acc0[j];
                Z[(size_t)(row0 + kb * 4 + j) * 128 + ct1 * 16 + rlo] = acc1[j];
            }
            // stats
            float s0 = acc0[0] + acc0[1] + acc0[2] + acc0[3];
            float q0 = acc0[0]*acc0[0] + acc0[1]*acc0[1] + acc0[2]*acc0[2] + acc0[3]*acc0[3];
            float s1 = acc1[0] + acc1[1] + acc1[2] + acc1[3];
            float q1 = acc1[0]*acc1[0] + acc1[1]*acc1[1] + acc1[2]*acc1[2] + acc1[3]*acc1[3];
            s0 += __shfl_xor(s0, 16); s0 += __shfl_xor(s0, 32);
            q0 += __shfl_xor(q0, 16); q0 += __shfl_xor(q0, 32);
            s1 += __shfl_xor(s1, 16); s1 += __shfl_xor(s1, 32);
            q1 += __shfl_xor(q1, 16); q1 += __shfl_xor(q1, 32);
            if (kb == 0) {
                atomicAdd(&sred[ct0 * 16 + rlo], s0);
                atomicAdd(&sred[128 + ct0 * 16 + rlo], q0);
                atomicAdd(&sred[ct1 * 16 + rlo], s1);
                atomicAdd(&sred[128 + ct1 * 16 + rlo], q1);
            }
        }
    }
    __syncthreads();
    if (tid < 128) {
        atomicAdd(&stats[tid], sred[tid]);
        atomicAdd(&stats[128 + tid], sred[128 + tid]);
    }
}

// ------------------------------------------------------------- BN finalize
__global__ void k_finalize(float* __restrict__ stats, const float* __restrict__ gamma,
                           const float* __restrict__ beta, float* __restrict__ ss, float invn) {
    int c = threadIdx.x;   // 128 threads
    float s = stats[c], qq = stats[128 + c];
    float m = s * invn;
    float var = fmaxf(qq * invn - m * m, 0.f);
    float rs = rsqrtf(var + BN_EPS);
    float sc = gamma[c] * rs;
    ss[c] = sc;
    ss[128 + c] = beta[c] - m * sc;
    stats[c] = 0.f;
    stats[128 + c] = 0.f;
}

// --------------------------------------------- segmented pooling (no atomics)
__global__ void k_pool_seg(const float* __restrict__ H, const int* __restrict__ gstart,
                           const float* __restrict__ ss, float* __restrict__ out) {
    int g = blockIdx.x;
    int s = gstart[g], e = gstart[g + 1];
    int t = threadIdx.x;
    int lane = t & 63, wave = t >> 6;
    int c0 = lane * 2;
    float sc0 = ss[c0], sc1 = ss[c0 + 1], sh0 = ss[128 + c0], sh1 = ss[129 + c0];
    const float2* Hp = (const float2*)H;
    float ax = 0.f, ay = 0.f;
    for (int r = s + wave; r < e; r += 4) {
        float2 v = Hp[(size_t)r * 64 + lane];
        ax += fmaxf(fmaf(v.x, sc0, sh0), 0.f);
        ay += fmaxf(fmaf(v.y, sc1, sh1), 0.f);
    }
    __shared__ float red[2][256];
    red[0][t] = ax;
    red[1][t] = ay;
    __syncthreads();
    if (wave == 0) {
        float inv = 1.f / fmaxf((float)(e - s), 1.f);
        float sx = red[0][lane] + red[0][64 + lane] + red[0][128 + lane] + red[0][192 + lane];
        float sy = red[1][lane] + red[1][64 + lane] + red[1][128 + lane] + red[1][192 + lane];
        out[g * 128 + c0] = sx * inv;
        out[g * 128 + c0 + 1] = sy * inv;
    }
}

// ----------------------------------------------------- final tiny GEMM (512x16)
__global__ void k_final(const float* __restrict__ Zh, const float* __restrict__ ss,
                        const float* __restrict__ Wc2, const float* __restrict__ bc2,
                        float* __restrict__ out) {
    __shared__ float Wl[128 * 16];
    __shared__ float Al[32 * 128];
    int tid = threadIdx.x;           // 512 threads, block handles 32 graphs
#pragma unroll
    for (int i = 0; i < 4; i++) Wl[tid + 512 * i] = Wc2[tid + 512 * i];
#pragma unroll
    for (int i = 0; i < 8; i++) {
        int idx = tid + 512 * i;
        int gl = idx >> 7, k = idx & 127;
        float a = Zh[(size_t)(blockIdx.x * 32 + gl) * 128 + k];
        Al[idx] = fmaxf(fmaf(a, ss[k], ss[128 + k]), 0.f);
    }
    __syncthreads();
    int g = tid >> 4, c = tid & 15;
    float acc = bc2[c];
#pragma unroll 8
    for (int k = 0; k < 128; k++) acc = fmaf(Al[g * 128 + k], Wl[k * 16 + c], acc);
    out[(size_t)(blockIdx.x * 32 + g) * 16 + c] = acc;
}

// ================================================================ launch
extern "C" void kernel_launch(void* const* d_in, const int* in_sizes, int n_in,
                              void* d_out, int out_size, void* d_ws, size_t ws_size,
                              hipStream_t stream) {
    (void)in_sizes; (void)n_in; (void)out_size; (void)ws_size;
    const float* x    = (const float*)d_in[0];
    const int*   ei   = (const int*)d_in[1];
    const int*   srcv = ei;
    const int*   dstv = ei + NE;
    const int*   batch = (const int*)d_in[2];
    const float* W1s = (const float*)d_in[3];
    const float* b1s = (const float*)d_in[4];
    const float* g1s = (const float*)d_in[5];
    const float* be1s = (const float*)d_in[6];
    const float* W2s = (const float*)d_in[7];
    const float* b2s = (const float*)d_in[8];
    const float* gns = (const float*)d_in[9];
    const float* bns = (const float*)d_in[10];
    const float* Wc1 = (const float*)d_in[11];
    const float* bc1 = (const float*)d_in[12];
    const float* gc  = (const float*)d_in[13];
    const float* bec = (const float*)d_in[14];
    const float* Wc2 = (const float*)d_in[15];
    const float* bc2 = (const float*)d_in[16];
    float* out = (float*)d_out;

    char* ws = (char*)d_ws;
    size_t off = 0;
    auto alloc = [&](size_t bytes) -> char* {
        char* p = ws + off;
        off += (bytes + 255) & ~(size_t)255;
        return p;
    };
    // --- zero zone (memset each launch) ---
    int*   deg    = (int*)alloc(50048 * 4);
    float* stats  = (float*)alloc(256 * 4);
    size_t zeroBytes = off;
    // --- rest ---
    int*   row_start = (int*)alloc((NN + 64) * 4);
    int*   cursor    = (int*)alloc((NN + 64) * 4);
    int*   pre       = (int*)alloc((NN + 64) * 4);
    int*   bsum      = (int*)alloc(64 * 4);
    int*   col       = (int*)alloc((NE + 64) * 4);
    int*   gstart    = (int*)alloc((NG + 1) * 4);
    float* ssA   = (float*)alloc(256 * 4);
    float* ssB   = (float*)alloc(256 * 4);
    float* headA = (float*)alloc(NG * 128 * 4);
    unsigned short* wfrag = (unsigned short*)alloc((size_t)7 * 2 * 16384 * 2);
    float* bufA  = (float*)alloc((size_t)NN * 128 * 4);
    float* bufB  = (float*)alloc((size_t)NN * 128 * 4);
    float* bufC  = (float*)alloc((size_t)NN * 128 * 4);

    hipMemsetAsync(d_ws, 0, zeroBytes, stream);

    // weight fragment prep (independent of CSR build)
    k_prepw<<<56, 256, 0, stream>>>(W1s, W2s, Wc1, wfrag);

    // CSR build (reused by all 3 layers) + graph boundaries
    k_hist<<<(NE + 255) / 256, 256, 0, stream>>>(dstv, deg, NE);
    int nb = (NN + 1023) / 1024;   // 49
    k_scan1<<<nb, 1024, 0, stream>>>(deg, pre, bsum, NN);
    k_scan2<<<1, 64, 0, stream>>>(bsum, nb);
    k_scan3<<<(NN + 255) / 256, 256, 0, stream>>>(pre, bsum, row_start, cursor, NN);
    k_scatter<<<(NE + 255) / 256, 256, 0, stream>>>(srcv, dstv, cursor, col, NE);
    k_gstart<<<(NN + 255) / 256, 256, 0, stream>>>(batch, gstart, NN);

    int aggGrid = (NN + 3) / 4;
    int nstrips = NN / 16;                      // 3125 (exact)
    int mfmaGrid = (nstrips + 3) / 4;           // 782
    for (int l = 0; l < 3; l++) {
        if (l == 0)
            k_aggregate<0><<<aggGrid, 256, 0, stream>>>(x, row_start, col, nullptr, bufA, NN);
        else
            k_aggregate<1><<<aggGrid, 256, 0, stream>>>(bufC, row_start, col, ssB, bufA, NN);
        k_gemm_mfma<0><<<mfmaGrid, 256, 0, stream>>>(bufA, wfrag + (size_t)(2 * l) * 16384,
                                                     b1s + l * 128, nullptr, bufB, stats, nstrips);
        k_finalize<<<1, 128, 0, stream>>>(stats, g1s + l * 128, be1s + l * 128, ssA, 1.f / NN);
        k_gemm_mfma<1><<<mfmaGrid, 256, 0, stream>>>(bufB, wfrag + (size_t)(2 * (3 + l)) * 16384,
                                                     b2s + l * 128, ssA, bufC, stats, nstrips);
        k_finalize<<<1, 128, 0, stream>>>(stats, gns + l * 128, bns + l * 128, ssB, 1.f / NN);
    }

    // pooling + head
    k_pool_seg<<<NG, 256, 0, stream>>>(bufC, gstart, ssB, headA);
    k_gemm_mfma<0><<<8, 256, 0, stream>>>(headA, wfrag + (size_t)12 * 16384,
                                          bc1, nullptr, bufB, stats, NG / 16);
    k_finalize<<<1, 128, 0, stream>>>(stats, gc, bec, ssA, 1.f / NG);
    k_final<<<16, 512, 0, stream>>>(bufB, ssA, Wc2, bc2, out);
}

// Round 5
// 433.994 us; speedup vs baseline: 1.9187x; 1.0607x over previous
//
#include <hip/hip_runtime.h>
#include <hip/hip_fp16.h>

#define NN 50000
#define NE 600000
#define DIM 128
#define NG 512
#define OC 16
#define BN_EPS 1e-5f

typedef __attribute__((ext_vector_type(8))) short short8v;   // 8 bf16 / 8 fp16 (4 VGPR)
typedef __attribute__((ext_vector_type(4))) float f32x4;

__device__ inline unsigned short f2bf(float f) {
    unsigned u = __float_as_uint(f);
    u = u + 0x7FFF + ((u >> 16) & 1);     // RNE
    return (unsigned short)(u >> 16);
}
__device__ inline float bf2f(unsigned short h) {
    return __uint_as_float(((unsigned)h) << 16);
}
__device__ inline float hbits2f(short s) {
    __half_raw hr; hr.x = (unsigned short)s;
    return __half2float(__half(hr));
}

// ---------------------------------------------------------------- histogram
__global__ void k_hist(const int* __restrict__ dst, int* __restrict__ deg, int e) {
    int i = blockIdx.x * blockDim.x + threadIdx.x;
    if (i < e) atomicAdd(&deg[dst[i]], 1);
}

// ----------------------------------------------- hierarchical scan
__global__ void k_scan1(const int* __restrict__ deg, int* __restrict__ pre,
                        int* __restrict__ bsum, int n) {
    __shared__ int lds[1024];
    int t = threadIdx.x;
    int i = blockIdx.x * 1024 + t;
    int v = (i < n) ? deg[i] : 0;
    lds[t] = v;
    __syncthreads();
#pragma unroll
    for (int off = 1; off < 1024; off <<= 1) {
        int add = (t >= off) ? lds[t - off] : 0;
        __syncthreads();
        lds[t] += add;
        __syncthreads();
    }
    if (i < n) pre[i] = lds[t] - v;
    if (t == 1023) bsum[blockIdx.x] = lds[1023];
}

__global__ void k_scan2(int* __restrict__ bsum, int nb) {
    int t = threadIdx.x;
    int v = (t < nb) ? bsum[t] : 0;
    int orig = v;
#pragma unroll
    for (int off = 1; off < 64; off <<= 1) {
        int u = __shfl_up(v, off);
        if (t >= off) v += u;
    }
    if (t < nb) bsum[t] = v - orig;
}

__global__ void k_scan3(const int* __restrict__ pre, const int* __restrict__ bsum,
                        int* __restrict__ row_start, int* __restrict__ cursor, int n) {
    int i = blockIdx.x * blockDim.x + threadIdx.x;
    if (i < n) {
        int r = pre[i] + bsum[i >> 10];
        row_start[i] = r;
        cursor[i] = r;
    }
    if (i == 0) row_start[n] = NE;
}

// ---------------------------------------------------------------- scatter
__global__ void k_scatter(const int* __restrict__ src, const int* __restrict__ dst,
                          int* __restrict__ cursor, int* __restrict__ col, int e) {
    int i = blockIdx.x * blockDim.x + threadIdx.x;
    if (i < e) {
        int d = dst[i];
        int p = atomicAdd(&cursor[d], 1);
        col[p] = src[i];
    }
}

// -------------------------------------------- graph boundaries (batch sorted)
__global__ void k_gstart(const int* __restrict__ batch, int* __restrict__ gstart, int n) {
    int i = blockIdx.x * blockDim.x + threadIdx.x;
    if (i >= n) return;
    int b = batch[i];
    int bp = (i == 0) ? -1 : batch[i - 1];
    for (int g = bp + 1; g <= b; g++) gstart[g] = i;
    if (i == n - 1) {
        for (int g = b + 1; g <= NG; g++) gstart[g] = n;
    }
}

// ------------------------------------------------ transform: fp32 -> fp16 table
// WITHBN: out = relu(in*sc+sh) with sc/sh from raw stats; else identity cast
template <int WITHBN>
__global__ void k_transform(const float* __restrict__ in, const float* __restrict__ stats,
                            const float* __restrict__ gamma, const float* __restrict__ beta,
                            float invn, __half* __restrict__ out, int n4) {
    int i = blockIdx.x * blockDim.x + threadIdx.x;
    if (i >= n4) return;
    float4 v = ((const float4*)in)[i];
    float f[4] = {v.x, v.y, v.z, v.w};
    if (WITHBN) {
        int c = (i & 31) * 4;
#pragma unroll
        for (int j = 0; j < 4; j++) {
            float s = stats[c + j], q = stats[128 + c + j];
            float m = s * invn;
            float var = fmaxf(q * invn - m * m, 0.f);
            float rs = rsqrtf(var + BN_EPS);
            float sc = gamma[c + j] * rs;
            float sh = beta[c + j] - m * sc;
            f[j] = fmaxf(fmaf(f[j], sc, sh), 0.f);
        }
    }
    __half2 o0 = __floats2half2_rn(f[0], f[1]);
    __half2 o1 = __floats2half2_rn(f[2], f[3]);
    uint2 pk;
    pk.x = *(unsigned*)&o0;
    pk.y = *(unsigned*)&o1;
    ((uint2*)out)[i] = pk;
}

// ------------------------------------------------------------- aggregation (fp16)
// out[i] = Ht[i] + sum_{j->i} Ht[j]   (table already transformed)
__global__ void k_aggregate_h(const __half* __restrict__ Ht, const int* __restrict__ rs,
                              const int* __restrict__ col, __half* __restrict__ out, int n) {
    int node = blockIdx.x * (blockDim.x >> 6) + (threadIdx.x >> 6);
    if (node >= n) return;
    int lane = threadIdx.x & 63;
    const __half2* Hp = (const __half2*)Ht;
    float2 a = __half22float2(Hp[(size_t)node * 64 + lane]);
    float ax = a.x, ay = a.y;
    int s = rs[node], e = rs[node + 1];
    int i = s;
    for (; i + 1 < e; i += 2) {
        int j0 = col[i], j1 = col[i + 1];
        float2 u0 = __half22float2(Hp[(size_t)j0 * 64 + lane]);
        float2 u1 = __half22float2(Hp[(size_t)j1 * 64 + lane]);
        ax += u0.x + u1.x;
        ay += u0.y + u1.y;
    }
    if (i < e) {
        float2 u0 = __half22float2(Hp[(size_t)col[i] * 64 + lane]);
        ax += u0.x;
        ay += u0.y;
    }
    ((__half2*)out)[(size_t)node * 64 + lane] = __floats2half2_rn(ax, ay);
}

// --------------------------------------------- weight -> MFMA fragment prep
// wfrag[(m*2+term)*16384 + ((ct*4+k0)*64+lane)*8 + j]
//   = bf16 hi/lo of W[k0*32+(lane>>4)*8+j][ct*16+(lane&15)]
__global__ void k_prepw(const float* __restrict__ W1s, const float* __restrict__ W2s,
                        const float* __restrict__ Wc1, unsigned short* __restrict__ wfrag) {
    int idx = blockIdx.x * blockDim.x + threadIdx.x;
    if (idx >= 7 * 8 * 4 * 64) return;
    int lane = idx & 63;
    int k0 = (idx >> 6) & 3;
    int ct = (idx >> 8) & 7;
    int m = idx >> 11;
    const float* Wsrc = (m < 3) ? (W1s + (size_t)m * 16384)
                      : (m < 6) ? (W2s + (size_t)(m - 3) * 16384)
                                : Wc1;
    int colc = ct * 16 + (lane & 15);
    int kbase = k0 * 32 + (lane >> 4) * 8;
    short8v hi, lo;
#pragma unroll
    for (int j = 0; j < 8; j++) {
        float w = Wsrc[(size_t)(kbase + j) * 128 + colc];
        unsigned short h = f2bf(w);
        hi[j] = (short)h;
        lo[j] = (short)f2bf(w - bf2f(h));
    }
    size_t fo = ((size_t)(ct * 4 + k0) * 64 + lane) * 8;
    *(short8v*)(wfrag + (size_t)(m * 2 + 0) * 16384 + fo) = hi;
    *(short8v*)(wfrag + (size_t)(m * 2 + 1) * 16384 + fo) = lo;
}

// --------------------------------------------- split-bf16 MFMA GEMM, LDS weights
// Z[n,128] = T(A[n,128]) @ W + bias; col sum/sumsq -> statsOut.
// A is fp16. TRANSFORM: BN(scale/shift from raw statsIn)+ReLU on A.
// ZHALF: write Z as fp16 else fp32.
#define MFMA(A8, B8, C4) __builtin_amdgcn_mfma_f32_16x16x32_bf16(A8, B8, C4, 0, 0, 0)

template <int TRANSFORM, int ZHALF>
__global__ __launch_bounds__(256) void k_gemm_mfma(
        const __half* __restrict__ A, const unsigned short* __restrict__ wfragm,
        const float* __restrict__ bias,
        const float* __restrict__ statsIn, const float* __restrict__ gamma,
        const float* __restrict__ beta, float invn,
        void* __restrict__ Zout, float* __restrict__ statsOut, int nstrips) {
    __shared__ short8v wldsHi[1024];   // 16 KB: [(ct'*4+k0)*64+lane], ct' = ct-4p
    __shared__ short8v wldsLo[1024];   // 16 KB
    __shared__ float sred[256];
    __shared__ float sst[256];
    int tid = threadIdx.x;
    int wid = tid >> 6, lane = tid & 63;
    int strip = blockIdx.x * 4 + wid;
    bool active = strip < nstrips;
    int row0 = strip * 16;
    int rlo = lane & 15, kb = lane >> 4;

    sred[tid] = 0.f;
    if (TRANSFORM && tid < 128) {
        float s = statsIn[tid], q = statsIn[128 + tid];
        float m = s * invn;
        float var = fmaxf(q * invn - m * m, 0.f);
        float rs = rsqrtf(var + BN_EPS);
        float sc = gamma[tid] * rs;
        sst[tid] = sc;
        sst[128 + tid] = beta[tid] - m * sc;
    }
    __syncthreads();

    // --- A fragments (fp16 -> exact bf16 hi/lo split) ---
    short8v ahi[4], alo[4];
    if (active) {
        const __half* ap = A + (size_t)(row0 + rlo) * 128;
#pragma unroll
        for (int k0 = 0; k0 < 4; k0++) {
            int c = k0 * 32 + kb * 8;
            short8v hv = *(const short8v*)(ap + c);
#pragma unroll
            for (int j = 0; j < 8; j++) {
                float f = hbits2f(hv[j]);
                if (TRANSFORM) f = fmaxf(fmaf(f, sst[c + j], sst[128 + c + j]), 0.f);
                unsigned short hb = f2bf(f);
                ahi[k0][j] = (short)hb;
                alo[k0][j] = (short)f2bf(f - bf2f(hb));
            }
        }
    }

    const float4* wsrc = (const float4*)wfragm;   // hi: 2048 f4, lo: +2048
    float4* dH = (float4*)wldsHi;
    float4* dL = (float4*)wldsLo;

#pragma unroll
    for (int p = 0; p < 2; p++) {
        // stage ct 4p..4p+3, hi+lo (16 KB each)
#pragma unroll
        for (int i = 0; i < 4; i++) {
            dH[tid + 256 * i] = wsrc[p * 1024 + tid + 256 * i];
            dL[tid + 256 * i] = wsrc[2048 + p * 1024 + tid + 256 * i];
        }
        __syncthreads();
        if (active) {
#pragma unroll
            for (int cc = 0; cc < 2; cc++) {
                int ctp = 2 * p + cc;
                int ct0 = ctp * 2, ct1 = ct0 + 1;
                int l0 = ct0 - 4 * p, l1 = ct1 - 4 * p;
                float bb0 = bias[ct0 * 16 + rlo], bb1 = bias[ct1 * 16 + rlo];
                f32x4 acc0 = {bb0, bb0, bb0, bb0};
                f32x4 acc1 = {bb1, bb1, bb1, bb1};
#pragma unroll
                for (int k0 = 0; k0 < 4; k0++) {
                    short8v bh0 = wldsHi[(l0 * 4 + k0) * 64 + lane];
                    short8v bh1 = wldsHi[(l1 * 4 + k0) * 64 + lane];
                    short8v bl0 = wldsLo[(l0 * 4 + k0) * 64 + lane];
                    short8v bl1 = wldsLo[(l1 * 4 + k0) * 64 + lane];
                    acc0 = MFMA(ahi[k0], bh0, acc0);
                    acc1 = MFMA(ahi[k0], bh1, acc1);
                    acc0 = MFMA(alo[k0], bh0, acc0);
                    acc1 = MFMA(alo[k0], bh1, acc1);
                    acc0 = MFMA(ahi[k0], bl0, acc0);
                    acc1 = MFMA(ahi[k0], bl1, acc1);
                }
                // store: C row = row0+kb*4+j, col = ct*16+rlo
#pragma unroll
                for (int j = 0; j < 4; j++) {
                    size_t i0 = (size_t)(row0 + kb * 4 + j) * 128 + ct0 * 16 + rlo;
                    size_t i1 = (size_t)(row0 + kb * 4 + j) * 128 + ct1 * 16 + rlo;
                    if (ZHALF) {
                        ((__half*)Zout)[i0] = __float2half(acc0[j]);
                        ((__half*)Zout)[i1] = __float2half(acc1[j]);
                    } else {
                        ((float*)Zout)[i0] = acc0[j];
                        ((float*)Zout)[i1] = acc1[j];
                    }
                }
                // column stats
                float s0 = acc0[0] + acc0[1] + acc0[2] + acc0[3];
                float q0 = acc0[0]*acc0[0] + acc0[1]*acc0[1] + acc0[2]*acc0[2] + acc0[3]*acc0[3];
                float s1 = acc1[0] + acc1[1] + acc1[2] + acc1[3];
                float q1 = acc1[0]*acc1[0] + acc1[1]*acc1[1] + acc1[2]*acc1[2] + acc1[3]*acc1[3];
                s0 += __shfl_xor(s0, 16); s0 += __shfl_xor(s0, 32);
                q0 += __shfl_xor(q0, 16); q0 += __shfl_xor(q0, 32);
                s1 += __shfl_xor(s1, 16); s1 += __shfl_xor(s1, 32);
                q1 += __shfl_xor(q1, 16); q1 += __shfl_xor(q1, 32);
                if (kb == 0) {
                    atomicAdd(&sred[ct0 * 16 + rlo], s0);
                    atomicAdd(&sred[128 + ct0 * 16 + rlo], q0);
                    atomicAdd(&sred[ct1 * 16 + rlo], s1);
                    atomicAdd(&sred[128 + ct1 * 16 + rlo], q1);
                }
            }
        }
        __syncthreads();
    }
    if (tid < 128) {
        atomicAdd(&statsOut[tid], sred[tid]);
        atomicAdd(&statsOut[128 + tid], sred[128 + tid]);
    }
}

// --------------------------------------------- segmented pooling, inline BN
__global__ void k_pool_seg(const float* __restrict__ H, const int* __restrict__ gstart,
                           const float* __restrict__ stats, const float* __restrict__ gamma,
                           const float* __restrict__ beta, float invn,
                           __half* __restrict__ out) {
    int g = blockIdx.x;
    int s = gstart[g], e = gstart[g + 1];
    int t = threadIdx.x;
    int lane = t & 63, wave = t >> 6;
    int c0 = lane * 2;
    float sc0, sc1, sh0, sh1;
    {
        float s0 = stats[c0], q0 = stats[128 + c0];
        float m0 = s0 * invn;
        float r0 = rsqrtf(fmaxf(q0 * invn - m0 * m0, 0.f) + BN_EPS);
        sc0 = gamma[c0] * r0; sh0 = beta[c0] - m0 * sc0;
        float s1 = stats[c0 + 1], q1 = stats[129 + c0];
        float m1 = s1 * invn;
        float r1 = rsqrtf(fmaxf(q1 * invn - m1 * m1, 0.f) + BN_EPS);
        sc1 = gamma[c0 + 1] * r1; sh1 = beta[c0 + 1] - m1 * sc1;
    }
    const float2* Hp = (const float2*)H;
    float ax = 0.f, ay = 0.f;
    for (int r = s + wave; r < e; r += 4) {
        float2 v = Hp[(size_t)r * 64 + lane];
        ax += fmaxf(fmaf(v.x, sc0, sh0), 0.f);
        ay += fmaxf(fmaf(v.y, sc1, sh1), 0.f);
    }
    __shared__ float red[2][256];
    red[0][t] = ax;
    red[1][t] = ay;
    __syncthreads();
    if (wave == 0) {
        float inv = 1.f / fmaxf((float)(e - s), 1.f);
        float sx = red[0][lane] + red[0][64 + lane] + red[0][128 + lane] + red[0][192 + lane];
        float sy = red[1][lane] + red[1][64 + lane] + red[1][128 + lane] + red[1][192 + lane];
        ((__half2*)out)[g * 64 + lane] = __floats2half2_rn(sx * inv, sy * inv);
    }
}

// ----------------------------------------------------- final tiny GEMM (512x16)
__global__ void k_final(const float* __restrict__ Zh, const float* __restrict__ stats,
                        const float* __restrict__ gamma, const float* __restrict__ beta,
                        float invn, const float* __restrict__ Wc2,
                        const float* __restrict__ bc2, float* __restrict__ out) {
    __shared__ float Wl[128 * 16];
    __shared__ float Al[32 * 128];
    int tid = threadIdx.x;           // 512 threads, block handles 32 graphs
    int kc = tid & 127;
    float s = stats[kc], q = stats[128 + kc];
    float m = s * invn;
    float rs = rsqrtf(fmaxf(q * invn - m * m, 0.f) + BN_EPS);
    float sck = gamma[kc] * rs;
    float shk = beta[kc] - m * sck;
#pragma unroll
    for (int i = 0; i < 4; i++) Wl[tid + 512 * i] = Wc2[tid + 512 * i];
#pragma unroll
    for (int i = 0; i < 8; i++) {
        int idx = tid + 512 * i;
        int gl = idx >> 7, k = idx & 127;
        float a = Zh[(size_t)(blockIdx.x * 32 + gl) * 128 + k];
        Al[idx] = fmaxf(fmaf(a, sck, shk), 0.f);
    }
    __syncthreads();
    int g = tid >> 4, c = tid & 15;
    float acc = bc2[c];
#pragma unroll 8
    for (int k = 0; k < 128; k++) acc = fmaf(Al[g * 128 + k], Wl[k * 16 + c], acc);
    out[(size_t)(blockIdx.x * 32 + g) * 16 + c] = acc;
}

// ================================================================ launch
extern "C" void kernel_launch(void* const* d_in, const int* in_sizes, int n_in,
                              void* d_out, int out_size, void* d_ws, size_t ws_size,
                              hipStream_t stream) {
    (void)in_sizes; (void)n_in; (void)out_size; (void)ws_size;
    const float* x    = (const float*)d_in[0];
    const int*   ei   = (const int*)d_in[1];
    const int*   srcv = ei;
    const int*   dstv = ei + NE;
    const int*   batch = (const int*)d_in[2];
    const float* W1s = (const float*)d_in[3];
    const float* b1s = (const float*)d_in[4];
    const float* g1s = (const float*)d_in[5];
    const float* be1s = (const float*)d_in[6];
    const float* W2s = (const float*)d_in[7];
    const float* b2s = (const float*)d_in[8];
    const float* gns = (const float*)d_in[9];
    const float* bns = (const float*)d_in[10];
    const float* Wc1 = (const float*)d_in[11];
    const float* bc1 = (const float*)d_in[12];
    const float* gc  = (const float*)d_in[13];
    const float* bec = (const float*)d_in[14];
    const float* Wc2 = (const float*)d_in[15];
    const float* bc2 = (const float*)d_in[16];
    float* out = (float*)d_out;

    char* ws = (char*)d_ws;
    size_t off = 0;
    auto alloc = [&](size_t bytes) -> char* {
        char* p = ws + off;
        off += (bytes + 255) & ~(size_t)255;
        return p;
    };
    // --- zero zone (memset each launch) ---
    int*   deg     = (int*)alloc(50048 * 4);
    float* statsZ  = (float*)alloc(7 * 256 * 4);   // s1[0..2], s2[0..2], head
    size_t zeroBytes = off;
    // --- rest ---
    int*   row_start = (int*)alloc((NN + 64) * 4);
    int*   cursor    = (int*)alloc((NN + 64) * 4);
    int*   pre       = (int*)alloc((NN + 64) * 4);
    int*   bsum      = (int*)alloc(64 * 4);
    int*   col       = (int*)alloc((NE + 64) * 4);
    int*   gstart    = (int*)alloc((NG + 1) * 4);
    unsigned short* wfrag = (unsigned short*)alloc((size_t)7 * 2 * 16384 * 2);
    __half* Ht    = (__half*)alloc((size_t)NN * 128 * 2);
    __half* aggH  = (__half*)alloc((size_t)NN * 128 * 2);
    __half* bufBh = (__half*)alloc((size_t)NN * 128 * 2);
    float*  bufC  = (float*)alloc((size_t)NN * 128 * 4);
    __half* headAh = (__half*)alloc((size_t)NG * 128 * 2);
    float*  bufF  = (float*)alloc((size_t)NG * 128 * 4);

    hipMemsetAsync(d_ws, 0, zeroBytes, stream);

    // weight fragment prep (independent of CSR build)
    k_prepw<<<56, 256, 0, stream>>>(W1s, W2s, Wc1, wfrag);

    // CSR build + graph boundaries
    k_hist<<<(NE + 255) / 256, 256, 0, stream>>>(dstv, deg, NE);
    int nb = (NN + 1023) / 1024;   // 49
    k_scan1<<<nb, 1024, 0, stream>>>(deg, pre, bsum, NN);
    k_scan2<<<1, 64, 0, stream>>>(bsum, nb);
    k_scan3<<<(NN + 255) / 256, 256, 0, stream>>>(pre, bsum, row_start, cursor, NN);
    k_scatter<<<(NE + 255) / 256, 256, 0, stream>>>(srcv, dstv, cursor, col, NE);
    k_gstart<<<(NN + 255) / 256, 256, 0, stream>>>(batch, gstart, NN);

    int n4 = NN * 32;                        // float4 count for transform
    int tGrid = (n4 + 255) / 256;
    int aggGrid = (NN + 3) / 4;
    int nstrips = NN / 16;                   // 3125 (exact)
    int mfmaGrid = (nstrips + 3) / 4;        // 782
    float invN = 1.f / NN;

    // x -> fp16 table (identity)
    k_transform<0><<<tGrid, 256, 0, stream>>>(x, nullptr, nullptr, nullptr, 0.f, Ht, n4);

    for (int l = 0; l < 3; l++) {
        float* s1 = statsZ + (size_t)(2 * l) * 256;
        float* s2 = statsZ + (size_t)(2 * l + 1) * 256;
        k_aggregate_h<<<aggGrid, 256, 0, stream>>>(Ht, row_start, col, aggH, NN);
        k_gemm_mfma<0, 1><<<mfmaGrid, 256, 0, stream>>>(
            aggH, wfrag + (size_t)(2 * l) * 16384, b1s + l * 128,
            nullptr, nullptr, nullptr, 0.f, bufBh, s1, nstrips);
        k_gemm_mfma<1, 0><<<mfmaGrid, 256, 0, stream>>>(
            bufBh, wfrag + (size_t)(2 * (3 + l)) * 16384, b2s + l * 128,
            s1, g1s + l * 128, be1s + l * 128, invN, bufC, s2, nstrips);
        if (l < 2)
            k_transform<1><<<tGrid, 256, 0, stream>>>(
                bufC, s2, gns + l * 128, bns + l * 128, invN, Ht, n4);
    }

    // pooling + head
    float* s2last = statsZ + (size_t)5 * 256;
    float* sHead  = statsZ + (size_t)6 * 256;
    k_pool_seg<<<NG, 256, 0, stream>>>(bufC, gstart, s2last, gns + 2 * 128,
                                       bns + 2 * 128, invN, headAh);
    k_gemm_mfma<0, 0><<<8, 256, 0, stream>>>(
        headAh, wfrag + (size_t)12 * 16384, bc1,
        nullptr, nullptr, nullptr, 0.f, bufF, sHead, NG / 16);
    k_final<<<16, 512, 0, stream>>>(bufF, sHead, gc, bec, 1.f / NG, Wc2, bc2, out);
}

// Round 6
// 341.268 us; speedup vs baseline: 2.4401x; 1.2717x over previous
//
#include <hip/hip_runtime.h>
#include <hip/hip_fp16.h>

#define NN 50000
#define NE 600000
#define DIM 128
#define NG 512
#define OC 16
#define BN_EPS 1e-5f

typedef __attribute__((ext_vector_type(8))) short short8v;   // 8 bf16 / 8 fp16 (4 VGPR)
typedef __attribute__((ext_vector_type(4))) float f32x4;

__device__ inline unsigned short f2bf(float f) {
    unsigned u = __float_as_uint(f);
    u = u + 0x7FFF + ((u >> 16) & 1);     // RNE
    return (unsigned short)(u >> 16);
}
__device__ inline float bf2f(unsigned short h) {
    return __uint_as_float(((unsigned)h) << 16);
}
__device__ inline float hbits2f(short s) {
    __half_raw hr; hr.x = (unsigned short)s;
    return __half2float(__half(hr));
}
__device__ inline short f2hbits(float f) {
    __half h = __float2half(f);
    short r;
    __builtin_memcpy(&r, &h, 2);
    return r;
}

// ---------------------------------------------------------------- histogram
__global__ void k_hist(const int* __restrict__ dst, int* __restrict__ deg, int e) {
    int i = blockIdx.x * blockDim.x + threadIdx.x;
    if (i < e) atomicAdd(&deg[dst[i]], 1);
}

// ----------------------------------------------- hierarchical scan
__global__ void k_scan1(const int* __restrict__ deg, int* __restrict__ pre,
                        int* __restrict__ bsum, int n) {
    __shared__ int lds[1024];
    int t = threadIdx.x;
    int i = blockIdx.x * 1024 + t;
    int v = (i < n) ? deg[i] : 0;
    lds[t] = v;
    __syncthreads();
#pragma unroll
    for (int off = 1; off < 1024; off <<= 1) {
        int add = (t >= off) ? lds[t - off] : 0;
        __syncthreads();
        lds[t] += add;
        __syncthreads();
    }
    if (i < n) pre[i] = lds[t] - v;
    if (t == 1023) bsum[blockIdx.x] = lds[1023];
}

__global__ void k_scan2(int* __restrict__ bsum, int nb) {
    int t = threadIdx.x;
    int v = (t < nb) ? bsum[t] : 0;
    int orig = v;
#pragma unroll
    for (int off = 1; off < 64; off <<= 1) {
        int u = __shfl_up(v, off);
        if (t >= off) v += u;
    }
    if (t < nb) bsum[t] = v - orig;
}

__global__ void k_scan3(const int* __restrict__ pre, const int* __restrict__ bsum,
                        int* __restrict__ row_start, int* __restrict__ cursor, int n) {
    int i = blockIdx.x * blockDim.x + threadIdx.x;
    if (i < n) {
        int r = pre[i] + bsum[i >> 10];
        row_start[i] = r;
        cursor[i] = r;
    }
    if (i == 0) row_start[n] = NE;
}

// ---------------------------------------------------------------- scatter
__global__ void k_scatter(const int* __restrict__ src, const int* __restrict__ dst,
                          int* __restrict__ cursor, int* __restrict__ col, int e) {
    int i = blockIdx.x * blockDim.x + threadIdx.x;
    if (i < e) {
        int d = dst[i];
        int p = atomicAdd(&cursor[d], 1);
        col[p] = src[i];
    }
}

// -------------------------------------------- graph boundaries (batch sorted)
__global__ void k_gstart(const int* __restrict__ batch, int* __restrict__ gstart, int n) {
    int i = blockIdx.x * blockDim.x + threadIdx.x;
    if (i >= n) return;
    int b = batch[i];
    int bp = (i == 0) ? -1 : batch[i - 1];
    for (int g = bp + 1; g <= b; g++) gstart[g] = i;
    if (i == n - 1) {
        for (int g = b + 1; g <= NG; g++) gstart[g] = n;
    }
}

// ------------------------------------------------ transform: fp32 -> fp16 table
__global__ void k_transform0(const float* __restrict__ in, __half* __restrict__ out, int n4) {
    int i = blockIdx.x * blockDim.x + threadIdx.x;
    if (i >= n4) return;
    float4 v = ((const float4*)in)[i];
    __half2 o0 = __floats2half2_rn(v.x, v.y);
    __half2 o1 = __floats2half2_rn(v.z, v.w);
    uint2 pk;
    pk.x = *(unsigned*)&o0;
    pk.y = *(unsigned*)&o1;
    ((uint2*)out)[i] = pk;
}

// ------------------------------------------------------------- aggregation
// Quarter-wave (16 lanes) per node; lane covers 8 cols (16 B loads).
// out[i] = T(H[i]) + sum_{j->i} T(H[j]); T = relu(x*sc+sh) from raw stats, or identity.
template <int TRANSFORM>
__global__ void k_aggregate_q(const __half* __restrict__ Ht, const int* __restrict__ rs,
                              const int* __restrict__ col,
                              const float* __restrict__ stats, const float* __restrict__ gamma,
                              const float* __restrict__ beta, float invn,
                              __half* __restrict__ out, int n) {
    __shared__ float sst[256];
    int tid = threadIdx.x;
    if (TRANSFORM && tid < 128) {
        float s = stats[tid], q = stats[128 + tid];
        float m = s * invn;
        float var = fmaxf(q * invn - m * m, 0.f);
        float r = rsqrtf(var + BN_EPS);
        float sc = gamma[tid] * r;
        sst[tid] = sc;
        sst[128 + tid] = beta[tid] - m * sc;
    }
    if (TRANSFORM) __syncthreads();

    int node = blockIdx.x * 16 + (tid >> 4);
    if (node >= n) return;
    int ql = tid & 15;
    int c = ql * 8;
    float sc[8], sh[8];
    if (TRANSFORM) {
#pragma unroll
        for (int j = 0; j < 8; j++) { sc[j] = sst[c + j]; sh[j] = sst[128 + c + j]; }
    }

    const short8v* Hp = (const short8v*)Ht;   // row = 16 short8v
    float acc[8];
    short8v hv = Hp[(size_t)node * 16 + ql];
#pragma unroll
    for (int j = 0; j < 8; j++) {
        float f = hbits2f(hv[j]);
        if (TRANSFORM) f = fmaxf(fmaf(f, sc[j], sh[j]), 0.f);
        acc[j] = f;
    }
    int s = rs[node], e = rs[node + 1];
    int i = s;
    for (; i + 1 < e; i += 2) {
        int j0 = col[i], j1 = col[i + 1];
        short8v u0 = Hp[(size_t)j0 * 16 + ql];
        short8v u1 = Hp[(size_t)j1 * 16 + ql];
#pragma unroll
        for (int j = 0; j < 8; j++) {
            float f0 = hbits2f(u0[j]);
            float f1 = hbits2f(u1[j]);
            if (TRANSFORM) {
                f0 = fmaxf(fmaf(f0, sc[j], sh[j]), 0.f);
                f1 = fmaxf(fmaf(f1, sc[j], sh[j]), 0.f);
            }
            acc[j] += f0 + f1;
        }
    }
    if (i < e) {
        short8v u0 = Hp[(size_t)col[i] * 16 + ql];
#pragma unroll
        for (int j = 0; j < 8; j++) {
            float f0 = hbits2f(u0[j]);
            if (TRANSFORM) f0 = fmaxf(fmaf(f0, sc[j], sh[j]), 0.f);
            acc[j] += f0;
        }
    }
    short8v o;
#pragma unroll
    for (int j = 0; j < 8; j++) o[j] = f2hbits(acc[j]);
    ((short8v*)out)[(size_t)node * 16 + ql] = o;
}

// --------------------------------------------- weight -> MFMA fragment prep
// wfrag[(m*2+term)*16384 + ((ct*4+k0)*64+lane)*8 + j]
//   = bf16 hi/lo of W[k0*32+(lane>>4)*8+j][ct*16+(lane&15)]
__global__ void k_prepw(const float* __restrict__ W1s, const float* __restrict__ W2s,
                        const float* __restrict__ Wc1, unsigned short* __restrict__ wfrag) {
    int idx = blockIdx.x * blockDim.x + threadIdx.x;
    if (idx >= 7 * 8 * 4 * 64) return;
    int lane = idx & 63;
    int k0 = (idx >> 6) & 3;
    int ct = (idx >> 8) & 7;
    int m = idx >> 11;
    const float* Wsrc = (m < 3) ? (W1s + (size_t)m * 16384)
                      : (m < 6) ? (W2s + (size_t)(m - 3) * 16384)
                                : Wc1;
    int colc = ct * 16 + (lane & 15);
    int kbase = k0 * 32 + (lane >> 4) * 8;
    short8v hi, lo;
#pragma unroll
    for (int j = 0; j < 8; j++) {
        float w = Wsrc[(size_t)(kbase + j) * 128 + colc];
        unsigned short h = f2bf(w);
        hi[j] = (short)h;
        lo[j] = (short)f2bf(w - bf2f(h));
    }
    size_t fo = ((size_t)(ct * 4 + k0) * 64 + lane) * 8;
    *(short8v*)(wfrag + (size_t)(m * 2 + 0) * 16384 + fo) = hi;
    *(short8v*)(wfrag + (size_t)(m * 2 + 1) * 16384 + fo) = lo;
}

// --------------------------------------------- split-bf16 MFMA GEMM, LDS weights
// Wave owns 2x16-row substrips (32 rows). A fp16. TRANSFORM: inline BN+ReLU on A.
#define MFMA(A8, B8, C4) __builtin_amdgcn_mfma_f32_16x16x32_bf16(A8, B8, C4, 0, 0, 0)

#define STORE_STATS(ACT, ACC0, ACC1, SUB)                                          \
    if (ACT) {                                                                     \
        int rowb = (SUB) * 16 + kb * 4;                                            \
        _Pragma("unroll")                                                          \
        for (int j = 0; j < 4; j++) {                                              \
            size_t i0 = (size_t)(rowb + j) * 128 + ct0 * 16 + rlo;                 \
            size_t i1 = (size_t)(rowb + j) * 128 + ct1 * 16 + rlo;                 \
            if (ZHALF) {                                                           \
                ((__half*)Zout)[i0] = __float2half(ACC0[j]);                       \
                ((__half*)Zout)[i1] = __float2half(ACC1[j]);                       \
            } else {                                                               \
                ((float*)Zout)[i0] = ACC0[j];                                      \
                ((float*)Zout)[i1] = ACC1[j];                                      \
            }                                                                      \
        }                                                                          \
        float s0 = ACC0[0] + ACC0[1] + ACC0[2] + ACC0[3];                          \
        float q0 = ACC0[0]*ACC0[0] + ACC0[1]*ACC0[1] + ACC0[2]*ACC0[2] + ACC0[3]*ACC0[3]; \
        float s1 = ACC1[0] + ACC1[1] + ACC1[2] + ACC1[3];                          \
        float q1 = ACC1[0]*ACC1[0] + ACC1[1]*ACC1[1] + ACC1[2]*ACC1[2] + ACC1[3]*ACC1[3]; \
        s0 += __shfl_xor(s0, 16); s0 += __shfl_xor(s0, 32);                        \
        q0 += __shfl_xor(q0, 16); q0 += __shfl_xor(q0, 32);                        \
        s1 += __shfl_xor(s1, 16); s1 += __shfl_xor(s1, 32);                        \
        q1 += __shfl_xor(q1, 16); q1 += __shfl_xor(q1, 32);                        \
        if (kb == 0) {                                                             \
            atomicAdd(&sred[ct0 * 16 + rlo], s0);                                  \
            atomicAdd(&sred[128 + ct0 * 16 + rlo], q0);                            \
            atomicAdd(&sred[ct1 * 16 + rlo], s1);                                  \
            atomicAdd(&sred[128 + ct1 * 16 + rlo], q1);                            \
        }                                                                          \
    }

template <int TRANSFORM, int ZHALF>
__global__ __launch_bounds__(256) void k_gemm_mfma(
        const __half* __restrict__ A, const unsigned short* __restrict__ wfragm,
        const float* __restrict__ bias,
        const float* __restrict__ statsIn, const float* __restrict__ gamma,
        const float* __restrict__ beta, float invn,
        void* __restrict__ Zout, float* __restrict__ statsOut, int nsub) {
    __shared__ short8v wldsHi[1024];   // 16 KB
    __shared__ short8v wldsLo[1024];   // 16 KB
    __shared__ float sred[256];
    __shared__ float sst[256];
    int tid = threadIdx.x;
    int wid = tid >> 6, lane = tid & 63;
    int sub0 = (blockIdx.x * 4 + wid) * 2;
    bool act0 = sub0 < nsub, act1 = sub0 + 1 < nsub;
    int rlo = lane & 15, kb = lane >> 4;

    sred[tid] = 0.f;
    if (TRANSFORM && tid < 128) {
        float s = statsIn[tid], q = statsIn[128 + tid];
        float m = s * invn;
        float var = fmaxf(q * invn - m * m, 0.f);
        float rs = rsqrtf(var + BN_EPS);
        float sc = gamma[tid] * rs;
        sst[tid] = sc;
        sst[128 + tid] = beta[tid] - m * sc;
    }
    __syncthreads();

    // --- A fragments for 2 substrips (fp16 -> exact bf16 hi/lo split) ---
    short8v ahi[2][4], alo[2][4];
#pragma unroll
    for (int ss = 0; ss < 2; ss++) {
        bool act = ss ? act1 : act0;
        if (act) {
            const __half* ap = A + ((size_t)(sub0 + ss) * 16 + rlo) * 128;
#pragma unroll
            for (int k0 = 0; k0 < 4; k0++) {
                int c = k0 * 32 + kb * 8;
                short8v hv = *(const short8v*)(ap + c);
#pragma unroll
                for (int j = 0; j < 8; j++) {
                    float f = hbits2f(hv[j]);
                    if (TRANSFORM) f = fmaxf(fmaf(f, sst[c + j], sst[128 + c + j]), 0.f);
                    unsigned short hb = f2bf(f);
                    ahi[ss][k0][j] = (short)hb;
                    alo[ss][k0][j] = (short)f2bf(f - bf2f(hb));
                }
            }
        } else {
#pragma unroll
            for (int k0 = 0; k0 < 4; k0++) {
                ahi[ss][k0] = short8v{0,0,0,0,0,0,0,0};
                alo[ss][k0] = short8v{0,0,0,0,0,0,0,0};
            }
        }
    }

    const float4* wsrc = (const float4*)wfragm;   // hi: 2048 f4, lo: +2048
    float4* dH = (float4*)wldsHi;
    float4* dL = (float4*)wldsLo;

#pragma unroll
    for (int p = 0; p < 2; p++) {
        if (p) __syncthreads();
#pragma unroll
        for (int i = 0; i < 4; i++) {
            dH[tid + 256 * i] = wsrc[p * 1024 + tid + 256 * i];
            dL[tid + 256 * i] = wsrc[2048 + p * 1024 + tid + 256 * i];
        }
        __syncthreads();
#pragma unroll
        for (int cc = 0; cc < 2; cc++) {
            int ctp = 2 * p + cc;
            int ct0 = ctp * 2, ct1 = ct0 + 1;
            int l0 = ct0 - 4 * p, l1 = ct1 - 4 * p;
            float bb0 = bias[ct0 * 16 + rlo], bb1 = bias[ct1 * 16 + rlo];
            f32x4 acc00 = {bb0, bb0, bb0, bb0};
            f32x4 acc01 = {bb1, bb1, bb1, bb1};
            f32x4 acc10 = {bb0, bb0, bb0, bb0};
            f32x4 acc11 = {bb1, bb1, bb1, bb1};
#pragma unroll
            for (int k0 = 0; k0 < 4; k0++) {
                short8v bh0 = wldsHi[(l0 * 4 + k0) * 64 + lane];
                short8v bh1 = wldsHi[(l1 * 4 + k0) * 64 + lane];
                short8v bl0 = wldsLo[(l0 * 4 + k0) * 64 + lane];
                short8v bl1 = wldsLo[(l1 * 4 + k0) * 64 + lane];
                acc00 = MFMA(ahi[0][k0], bh0, acc00);
                acc10 = MFMA(ahi[1][k0], bh0, acc10);
                acc01 = MFMA(ahi[0][k0], bh1, acc01);
                acc11 = MFMA(ahi[1][k0], bh1, acc11);
                acc00 = MFMA(alo[0][k0], bh0, acc00);
                acc10 = MFMA(alo[1][k0], bh0, acc10);
                acc01 = MFMA(alo[0][k0], bh1, acc01);
                acc11 = MFMA(alo[1][k0], bh1, acc11);
                acc00 = MFMA(ahi[0][k0], bl0, acc00);
                acc10 = MFMA(ahi[1][k0], bl0, acc10);
                acc01 = MFMA(ahi[0][k0], bl1, acc01);
                acc11 = MFMA(ahi[1][k0], bl1, acc11);
            }
            STORE_STATS(act0, acc00, acc01, sub0);
            STORE_STATS(act1, acc10, acc11, sub0 + 1);
        }
    }
    __syncthreads();
    if (tid < 128) {
        atomicAdd(&statsOut[tid], sred[tid]);
        atomicAdd(&statsOut[128 + tid], sred[128 + tid]);
    }
}

// --------------------------------------------- segmented pooling, inline BN (fp16 in)
__global__ void k_pool_seg(const __half* __restrict__ H, const int* __restrict__ gstart,
                           const float* __restrict__ stats, const float* __restrict__ gamma,
                           const float* __restrict__ beta, float invn,
                           __half* __restrict__ out) {
    int g = blockIdx.x;
    int s = gstart[g], e = gstart[g + 1];
    int t = threadIdx.x;
    int lane = t & 63, wave = t >> 6;
    int c0 = lane * 2;
    float sc0, sc1, sh0, sh1;
    {
        float s0 = stats[c0], q0 = stats[128 + c0];
        float m0 = s0 * invn;
        float r0 = rsqrtf(fmaxf(q0 * invn - m0 * m0, 0.f) + BN_EPS);
        sc0 = gamma[c0] * r0; sh0 = beta[c0] - m0 * sc0;
        float s1 = stats[c0 + 1], q1 = stats[129 + c0];
        float m1 = s1 * invn;
        float r1 = rsqrtf(fmaxf(q1 * invn - m1 * m1, 0.f) + BN_EPS);
        sc1 = gamma[c0 + 1] * r1; sh1 = beta[c0 + 1] - m1 * sc1;
    }
    const __half2* Hp = (const __half2*)H;
    float ax = 0.f, ay = 0.f;
    for (int r = s + wave; r < e; r += 4) {
        float2 v = __half22float2(Hp[(size_t)r * 64 + lane]);
        ax += fmaxf(fmaf(v.x, sc0, sh0), 0.f);
        ay += fmaxf(fmaf(v.y, sc1, sh1), 0.f);
    }
    __shared__ float red[2][256];
    red[0][t] = ax;
    red[1][t] = ay;
    __syncthreads();
    if (wave == 0) {
        float inv = 1.f / fmaxf((float)(e - s), 1.f);
        float sx = red[0][lane] + red[0][64 + lane] + red[0][128 + lane] + red[0][192 + lane];
        float sy = red[1][lane] + red[1][64 + lane] + red[1][128 + lane] + red[1][192 + lane];
        ((__half2*)out)[g * 64 + lane] = __floats2half2_rn(sx * inv, sy * inv);
    }
}

// ----------------------------------------------------- final tiny GEMM (512x16)
__global__ void k_final(const float* __restrict__ Zh, const float* __restrict__ stats,
                        const float* __restrict__ gamma, const float* __restrict__ beta,
                        float invn, const float* __restrict__ Wc2,
                        const float* __restrict__ bc2, float* __restrict__ out) {
    __shared__ float Wl[128 * 16];
    __shared__ float Al[32 * 128];
    int tid = threadIdx.x;           // 512 threads, block handles 32 graphs
    int kc = tid & 127;
    float s = stats[kc], q = stats[128 + kc];
    float m = s * invn;
    float rs = rsqrtf(fmaxf(q * invn - m * m, 0.f) + BN_EPS);
    float sck = gamma[kc] * rs;
    float shk = beta[kc] - m * sck;
#pragma unroll
    for (int i = 0; i < 4; i++) Wl[tid + 512 * i] = Wc2[tid + 512 * i];
#pragma unroll
    for (int i = 0; i < 8; i++) {
        int idx = tid + 512 * i;
        int gl = idx >> 7, k = idx & 127;
        float a = Zh[(size_t)(blockIdx.x * 32 + gl) * 128 + k];
        Al[idx] = fmaxf(fmaf(a, sck, shk), 0.f);
    }
    __syncthreads();
    int g = tid >> 4, c = tid & 15;
    float acc = bc2[c];
#pragma unroll 8
    for (int k = 0; k < 128; k++) acc = fmaf(Al[g * 128 + k], Wl[k * 16 + c], acc);
    out[(size_t)(blockIdx.x * 32 + g) * 16 + c] = acc;
}

// ================================================================ launch
extern "C" void kernel_launch(void* const* d_in, const int* in_sizes, int n_in,
                              void* d_out, int out_size, void* d_ws, size_t ws_size,
                              hipStream_t stream) {
    (void)in_sizes; (void)n_in; (void)out_size; (void)ws_size;
    const float* x    = (const float*)d_in[0];
    const int*   ei   = (const int*)d_in[1];
    const int*   srcv = ei;
    const int*   dstv = ei + NE;
    const int*   batch = (const int*)d_in[2];
    const float* W1s = (const float*)d_in[3];
    const float* b1s = (const float*)d_in[4];
    const float* g1s = (const float*)d_in[5];
    const float* be1s = (const float*)d_in[6];
    const float* W2s = (const float*)d_in[7];
    const float* b2s = (const float*)d_in[8];
    const float* gns = (const float*)d_in[9];
    const float* bns = (const float*)d_in[10];
    const float* Wc1 = (const float*)d_in[11];
    const float* bc1 = (const float*)d_in[12];
    const float* gc  = (const float*)d_in[13];
    const float* bec = (const float*)d_in[14];
    const float* Wc2 = (const float*)d_in[15];
    const float* bc2 = (const float*)d_in[16];
    float* out = (float*)d_out;

    char* ws = (char*)d_ws;
    size_t off = 0;
    auto alloc = [&](size_t bytes) -> char* {
        char* p = ws + off;
        off += (bytes + 255) & ~(size_t)255;
        return p;
    };
    // --- zero zone (memset each launch) ---
    int*   deg     = (int*)alloc(50048 * 4);
    float* statsZ  = (float*)alloc(7 * 256 * 4);   // s1_l at 2l, s2_l at 2l+1, head at 6
    size_t zeroBytes = off;
    // --- rest ---
    int*   row_start = (int*)alloc((NN + 64) * 4);
    int*   cursor    = (int*)alloc((NN + 64) * 4);
    int*   pre       = (int*)alloc((NN + 64) * 4);
    int*   bsum      = (int*)alloc(64 * 4);
    int*   col       = (int*)alloc((NE + 64) * 4);
    int*   gstart    = (int*)alloc((NG + 1) * 4);
    unsigned short* wfrag = (unsigned short*)alloc((size_t)7 * 2 * 16384 * 2);
    __half* Ht     = (__half*)alloc((size_t)NN * 128 * 2);
    __half* aggH   = (__half*)alloc((size_t)NN * 128 * 2);
    __half* bufBh  = (__half*)alloc((size_t)NN * 128 * 2);
    __half* bufCh  = (__half*)alloc((size_t)NN * 128 * 2);
    __half* headAh = (__half*)alloc((size_t)NG * 128 * 2);
    float*  bufF   = (float*)alloc((size_t)NG * 128 * 4);

    hipMemsetAsync(d_ws, 0, zeroBytes, stream);

    // weight fragment prep (independent of CSR build)
    k_prepw<<<56, 256, 0, stream>>>(W1s, W2s, Wc1, wfrag);

    // CSR build + graph boundaries
    k_hist<<<(NE + 255) / 256, 256, 0, stream>>>(dstv, deg, NE);
    int nb = (NN + 1023) / 1024;   // 49
    k_scan1<<<nb, 1024, 0, stream>>>(deg, pre, bsum, NN);
    k_scan2<<<1, 64, 0, stream>>>(bsum, nb);
    k_scan3<<<(NN + 255) / 256, 256, 0, stream>>>(pre, bsum, row_start, cursor, NN);
    k_scatter<<<(NE + 255) / 256, 256, 0, stream>>>(srcv, dstv, cursor, col, NE);
    k_gstart<<<(NN + 255) / 256, 256, 0, stream>>>(batch, gstart, NN);

    int n4 = NN * 32;
    int tGrid = (n4 + 255) / 256;
    int aggGrid = NN / 16;                   // 3125 exact (16 nodes per 256-thr block)
    int nsub = NN / 16;                      // 3125 16-row substrips (exact)
    int gGrid = (nsub + 7) / 8;              // 391 blocks (8 substrips each)
    float invN = 1.f / NN;

    // x -> fp16 table (identity)
    k_transform0<<<tGrid, 256, 0, stream>>>(x, Ht, n4);

    for (int l = 0; l < 3; l++) {
        float* s1 = statsZ + (size_t)(2 * l) * 256;
        float* s2 = statsZ + (size_t)(2 * l + 1) * 256;
        if (l == 0)
            k_aggregate_q<0><<<aggGrid, 256, 0, stream>>>(
                Ht, row_start, col, nullptr, nullptr, nullptr, 0.f, aggH, NN);
        else
            k_aggregate_q<1><<<aggGrid, 256, 0, stream>>>(
                bufCh, row_start, col, statsZ + (size_t)(2 * l - 1) * 256,
                gns + (l - 1) * 128, bns + (l - 1) * 128, invN, aggH, NN);
        k_gemm_mfma<0, 1><<<gGrid, 256, 0, stream>>>(
            aggH, wfrag + (size_t)(2 * l) * 16384, b1s + l * 128,
            nullptr, nullptr, nullptr, 0.f, bufBh, s1, nsub);
        k_gemm_mfma<1, 1><<<gGrid, 256, 0, stream>>>(
            bufBh, wfrag + (size_t)(2 * (3 + l)) * 16384, b2s + l * 128,
            s1, g1s + l * 128, be1s + l * 128, invN, bufCh, s2, nsub);
    }

    // pooling + head
    float* s2last = statsZ + (size_t)5 * 256;
    float* sHead  = statsZ + (size_t)6 * 256;
    k_pool_seg<<<NG, 256, 0, stream>>>(bufCh, gstart, s2last, gns + 2 * 128,
                                       bns + 2 * 128, invN, headAh);
    k_gemm_mfma<0, 0><<<4, 256, 0, stream>>>(
        headAh, wfrag + (size_t)12 * 16384, bc1,
        nullptr, nullptr, nullptr, 0.f, bufF, sHead, NG / 16);
    k_final<<<16, 512, 0, stream>>>(bufF, sHead, gc, bec, 1.f / NG, Wc2, bc2, out);
}